// Round 7
// baseline (230.021 us; speedup 1.0000x reference)
//
#include <hip/hip_runtime.h>
#include <hip/hip_bf16.h>

// B=2, N=2048, C=1024, H=16, hd=64, M=4096. bf16 MFMA path (threshold 2%).

typedef __attribute__((ext_vector_type(8))) short short8;
typedef __attribute__((ext_vector_type(4))) short short4v;
typedef __attribute__((ext_vector_type(4))) float float4v;
typedef __attribute__((ext_vector_type(4))) unsigned uint4v;

__device__ __forceinline__ unsigned short f2bf(float f) {   // RTNE
    unsigned u = __builtin_bit_cast(unsigned, f);
    return (unsigned short)((u + 0x7FFFu + ((u >> 16) & 1u)) >> 16);
}
// pack two f32 -> two bf16 (round-half-up) in one dword via v_perm
__device__ __forceinline__ unsigned packbf2(float lo, float hi) {
    return __builtin_amdgcn_perm(__builtin_bit_cast(unsigned, hi) + 0x8000u,
                                 __builtin_bit_cast(unsigned, lo) + 0x8000u,
                                 0x07060302u);
}
__device__ __forceinline__ void gll16(const unsigned short* g, unsigned short* l) {
    __builtin_amdgcn_global_load_lds(
        (const __attribute__((address_space(1))) unsigned int*)g,
        (__attribute__((address_space(3))) unsigned int*)l, 16, 0, 0);
}

// ---------------- prep: ln1 (blocks 0..4095) + weight transposes.
__global__ __launch_bounds__(256) void prep(
    const float* __restrict__ x, const float* __restrict__ g1, const float* __restrict__ b1,
    const float* __restrict__ w_qk, const float* __restrict__ w_v,
    const float* __restrict__ w_proj, const float* __restrict__ g2,
    const float* __restrict__ b2,
    unsigned short* __restrict__ xn, unsigned short* __restrict__ wqkvT,
    unsigned short* __restrict__ wgT, float* __restrict__ u, float* __restrict__ w0) {
    __shared__ float sh[32 * 33];
    const int bid = blockIdx.x, tid = threadIdx.x;
    if (bid < 4096) {                       // ---- LN1 row
        const float4 v = reinterpret_cast<const float4*>(x + (size_t)bid * 1024)[tid];
        float s  = v.x + v.y + v.z + v.w;
        float sq = v.x * v.x + v.y * v.y + v.z * v.z + v.w * v.w;
#pragma unroll
        for (int off = 32; off >= 1; off >>= 1) {
            s  += __shfl_xor(s, off, 64);
            sq += __shfl_xor(sq, off, 64);
        }
        const int w = tid >> 6, lane = tid & 63;
        if (lane == 0) { sh[w] = s; sh[4 + w] = sq; }
        __syncthreads();
        s  = sh[0] + sh[1] + sh[2] + sh[3];
        sq = sh[4] + sh[5] + sh[6] + sh[7];
        const float mu = s * (1.f / 1024.f);
        const float rstd = rsqrtf(sq * (1.f / 1024.f) - mu * mu + 1e-5f);
        const float4 gv = reinterpret_cast<const float4*>(g1)[tid];
        const float4 bv = reinterpret_cast<const float4*>(b1)[tid];
        ushort4 o;
        o.x = f2bf((v.x - mu) * rstd * gv.x + bv.x);
        o.y = f2bf((v.y - mu) * rstd * gv.y + bv.y);
        o.z = f2bf((v.z - mu) * rstd * gv.z + bv.z);
        o.w = f2bf((v.w - mu) * rstd * gv.w + bv.w);
        *reinterpret_cast<ushort4*>(&xn[(size_t)bid * 1024 + tid * 4]) = o;
    } else {                                // ---- transpose f32[1024][Cc] -> bf16[Cc][1024]
        const float* in; unsigned short* out; int Cc, bx, by; bool doU = false;
        if (bid < 6144)      { int t = bid - 4096; in = w_qk;   out = wqkvT;               Cc = 2048; bx = t & 63; by = t >> 6; }
        else if (bid < 7168) { int t = bid - 6144; in = w_v;    out = wqkvT + 2048 * 1024; Cc = 1024; bx = t & 31; by = t >> 5; }
        else                 { int t = bid - 7168; in = w_proj; out = wgT; doU = true;     Cc = 1024; bx = t & 31; by = t >> 5; }
        const int c0 = bx * 32, r0 = by * 32;
        const int tx = tid & 31, ty = tid >> 5;
#pragma unroll
        for (int i = 0; i < 32; i += 8)
            sh[(ty + i) * 33 + tx] = in[(size_t)(r0 + ty + i) * Cc + c0 + tx];
        __syncthreads();
        // out col = original row index c = r0+tx
        const float scale = doU ? g2[r0 + tx] : 1.f;
        const float b2v   = doU ? b2[r0 + tx] : 0.f;
#pragma unroll
        for (int i = 0; i < 32; i += 8) {
            const float raw = sh[tx * 33 + ty + i];
            const float sc  = raw * scale;
            out[(size_t)(c0 + ty + i) * 1024 + r0 + tx] = f2bf(sc);
            if (doU) {
                float pu = sc, pw = raw * b2v;    // per-c contributions for j=c0+ty+i
#pragma unroll
                for (int off = 1; off <= 16; off <<= 1) {   // reduce over tx (32 lanes)
                    pu += __shfl_xor(pu, off, 64);
                    pw += __shfl_xor(pw, off, 64);
                }
                if (tx == 0) {
                    atomicAdd(&u[c0 + ty + i], pu);
                    atomicAdd(&w0[c0 + ty + i], pw);
                }
            }
        }
    }
}

// ---------------- GEMM1: 256x256 tile, 512 threads, double-buffered.
__global__ __launch_bounds__(512) void gemm256_qkv(const unsigned short* __restrict__ A,
                                                   const unsigned short* __restrict__ Bt,
                                                   unsigned short* __restrict__ qb,
                                                   unsigned short* __restrict__ kb,
                                                   unsigned short* __restrict__ vT) {
    __shared__ unsigned short As[2 * 256 * 64], Bs[2 * 256 * 64];   // 128 KB
    const int tid = threadIdx.x, lane = tid & 63, w = tid >> 6;     // w 0..7
    const int wm = (w >> 2) * 128, wn = (w & 3) * 64;
    const int quad = lane >> 4, l16 = lane & 15;
    const int ls = lane >> 3, sg = lane & 7;
    const int m0 = blockIdx.y * 256, n0 = blockIdx.x * 256;

    float4v acc[8][4];
#pragma unroll
    for (int mi = 0; mi < 8; mi++)
#pragma unroll
        for (int ni = 0; ni < 4; ni++) acc[mi][ni] = float4v{0.f, 0.f, 0.f, 0.f};

    const int g = (sg ^ ls) * 8;
#pragma unroll 1
    for (int s = -1; s < 16; s++) {
        if (s >= 0) __syncthreads();
        if (s + 1 < 16) {                   // stage step s+1
            const int k0 = (s + 1) << 6, buf = ((s + 1) & 1) << 14;
            unsigned short* Ad = As + buf;
            unsigned short* Bd = Bs + buf;
#pragma unroll
            for (int i = 0; i < 4; i++) {
                const int r = w * 32 + i * 8 + ls;      // r&7 == ls
                gll16(&A[(size_t)(m0 + r) * 1024 + k0 + g], &Ad[(w * 32 + i * 8) * 64]);
                gll16(&Bt[(size_t)(n0 + r) * 1024 + k0 + g], &Bd[(w * 32 + i * 8) * 64]);
            }
        }
        if (s < 0) continue;
        const unsigned short* Ac = As + ((s & 1) << 14);
        const unsigned short* Bc = Bs + ((s & 1) << 14);
#pragma unroll
        for (int ks = 0; ks < 2; ks++) {
            short8 af[8], bfr[4];
#pragma unroll
            for (int mi = 0; mi < 8; mi++) {
                const int r = wm + mi * 16 + l16;
                af[mi] = *reinterpret_cast<const short8*>(
                    &Ac[r * 64 + ((ks * 4 + quad) ^ (r & 7)) * 8]);
            }
#pragma unroll
            for (int ni = 0; ni < 4; ni++) {
                const int r = wn + ni * 16 + l16;
                bfr[ni] = *reinterpret_cast<const short8*>(
                    &Bc[r * 64 + ((ks * 4 + quad) ^ (r & 7)) * 8]);
            }
#pragma unroll
            for (int mi = 0; mi < 8; mi++)
#pragma unroll
                for (int ni = 0; ni < 4; ni++)
                    acc[mi][ni] = __builtin_amdgcn_mfma_f32_16x16x32_bf16(
                        af[mi], bfr[ni], acc[mi][ni], 0, 0, 0);
        }
    }

    const float QSCALE = 0.125f * 1.4426950408889634f;  // hd^-0.5 * log2(e)
#pragma unroll
    for (int mi = 0; mi < 8; mi++) {
        const int row0 = m0 + wm + mi * 16 + quad * 4;
        const int b = row0 >> 11, nq = row0 & 2047;
#pragma unroll
        for (int ni = 0; ni < 4; ni++) {
            const int col = n0 + wn + ni * 16 + l16;
            if (col < 1024) {             // q: [bh][n][d]
                const int h = col >> 6, d = col & 63;
#pragma unroll
                for (int r = 0; r < 4; r++)
                    qb[(((size_t)b * 16 + h) * 2048 + nq + r) * 64 + d] =
                        f2bf(acc[mi][ni][r] * QSCALE);
            } else if (col < 2048) {      // k: [bh][n][d]
                const int c = col - 1024, h = c >> 6, d = c & 63;
#pragma unroll
                for (int r = 0; r < 4; r++)
                    kb[(((size_t)b * 16 + h) * 2048 + nq + r) * 64 + d] = f2bf(acc[mi][ni][r]);
            } else {                      // v^T: [bh][d][n], 4 consecutive keys -> 8B store
                const int c = col - 2048, h = c >> 6, d = c & 63;
                const short4v sv = {(short)f2bf(acc[mi][ni][0]), (short)f2bf(acc[mi][ni][1]),
                                    (short)f2bf(acc[mi][ni][2]), (short)f2bf(acc[mi][ni][3])};
                *reinterpret_cast<short4v*>(
                    &vT[(((size_t)b * 16 + h) * 64 + d) * 2048 + nq]) = sv;
            }
        }
    }
}

// ---------------- flash attention v5: O^T = V^T P^T formulation.
// S^T = K Q^T with K rows staged PERMUTED so that the S^T C-register at
// (cb,quad,reg) holds key (cb>>1)*32 + quad*8 + (cb&1)*4 + reg — exactly the
// B-operand k-order for a full-rate 16x16x32 PV mfma, P direct from regs.
// V^T rows are the A-operand (16B contiguous) -> loaded straight from global
// (L2-resident), NO LDS for V. Only K staged (dbuf, 16 KB). Q-tile 128,
// 256 thr, grid 512 = 2 blocks/CU (R6 lesson: never 1 block/CU).
__global__ __launch_bounds__(256) void flash_attn(const unsigned short* __restrict__ qbuf,
                                                  const unsigned short* __restrict__ kb,
                                                  const unsigned short* __restrict__ vT,
                                                  unsigned short* __restrict__ attn,
                                                  float2* __restrict__ part) {
    __shared__ unsigned short Ks[2][64 * 64];   // K tile, permuted rows, XOR-swizzled
    const int tid = threadIdx.x, lane = tid & 63, w = tid >> 6;   // w 0..3
    const int quad = lane >> 4, l16 = lane & 15;
    const int ls = lane >> 3, sg = lane & 7;
    const int q0 = blockIdx.x * 128, bh = blockIdx.y;
    const size_t nbase = (size_t)bh * 2048;

    // staging source rows: phys row pr holds actual key ka(pr)
    // ka = [bit5][quad(2b)][cb&1][reg(2b)] from pr = [bit5][cb&1][quad][reg]
    int srow[2];
#pragma unroll
    for (int i = 0; i < 2; i++) {
        const int pr = w * 16 + i * 8 + ls;
        srow[i] = (pr & 32) | ((pr & 12) << 1) | ((pr & 16) >> 2) | (pr & 3);
    }
    const int sgran = (sg ^ ls) << 3;

    short8 bq[2][2];   // Q as B-operand for two 16-q subblocks (q = w*32+q2*16+l16)
#pragma unroll
    for (int q2 = 0; q2 < 2; q2++)
#pragma unroll
        for (int ks = 0; ks < 2; ks++)
            bq[q2][ks] = *reinterpret_cast<const short8*>(
                &qbuf[(nbase + q0 + w * 32 + q2 * 16 + l16) * 64 + ks * 32 + quad * 8]);

    float l_part[2] = {0.f, 0.f};
    float4v o_acc[2][4];   // o_acc[q2][db][reg]: d = db*16+quad*4+reg, q = l16
#pragma unroll
    for (int q2 = 0; q2 < 2; q2++)
#pragma unroll
        for (int db = 0; db < 4; db++) o_acc[q2][db] = float4v{0.f, 0.f, 0.f, 0.f};

    // stage tile 0
#pragma unroll
    for (int i = 0; i < 2; i++)
        gll16(&kb[(nbase + srow[i]) * 64 + sgran], &Ks[0][(w * 16 + i * 8) * 64]);

#pragma unroll 1
    for (int s = 0; s < 32; s++) {
        const int kt0 = s << 6;
        __syncthreads();                    // drains K DMA for tile s
        if (s + 1 < 32) {                   // stage K tile s+1 (drained next barrier)
            const int ktn = (s + 1) << 6;
#pragma unroll
            for (int i = 0; i < 2; i++)
                gll16(&kb[(nbase + ktn + srow[i]) * 64 + sgran],
                      &Ks[(s + 1) & 1][(w * 16 + i * 8) * 64]);
        }
        // V^T A-fragments direct from global (hidden behind QK+softmax)
        short8 va[2][4];
#pragma unroll
        for (int k2 = 0; k2 < 2; k2++)
#pragma unroll
            for (int db = 0; db < 4; db++)
                va[k2][db] = *reinterpret_cast<const short8*>(
                    &vT[((size_t)bh * 64 + db * 16 + l16) * 2048 + kt0 + k2 * 32 + quad * 8]);

        const unsigned short* Kc = Ks[s & 1];
        short8 kf[2][4];
#pragma unroll
        for (int ks = 0; ks < 2; ks++)
#pragma unroll
            for (int cb = 0; cb < 4; cb++) {
                const int r = cb * 16 + l16;
                kf[ks][cb] = *reinterpret_cast<const short8*>(
                    &Kc[r * 64 + ((ks * 4 + quad) ^ (r & 7)) * 8]);
            }

#pragma unroll
        for (int q2 = 0; q2 < 2; q2++) {
            float4v s_acc[4];
#pragma unroll
            for (int cb = 0; cb < 4; cb++) s_acc[cb] = float4v{0.f, 0.f, 0.f, 0.f};
#pragma unroll
            for (int ks = 0; ks < 2; ks++)
#pragma unroll
                for (int cb = 0; cb < 4; cb++)
                    s_acc[cb] = __builtin_amdgcn_mfma_f32_16x16x32_bf16(
                        kf[ks][cb], bq[q2][ks], s_acc[cb], 0, 0, 0);

            // fixed-max softmax: p = 2^s (s hard-bounded, O/l cancels).
            // pack P^T B-operand: k = quad*8 + (cb&1)*4 + reg
            float ls2 = 0.f;
            short8 pb[2];
#pragma unroll
            for (int k2 = 0; k2 < 2; k2++) {
                float p[8];
#pragma unroll
                for (int cc = 0; cc < 2; cc++)
#pragma unroll
                    for (int r = 0; r < 4; r++) {
                        const float pv = __builtin_amdgcn_exp2f(s_acc[k2 * 2 + cc][r]);
                        p[cc * 4 + r] = pv;
                        ls2 += pv;
                    }
                uint4v pd;
                pd.x = packbf2(p[0], p[1]); pd.y = packbf2(p[2], p[3]);
                pd.z = packbf2(p[4], p[5]); pd.w = packbf2(p[6], p[7]);
                pb[k2] = __builtin_bit_cast(short8, pd);
            }
            l_part[q2] += ls2;
#pragma unroll
            for (int k2 = 0; k2 < 2; k2++)
#pragma unroll
                for (int db = 0; db < 4; db++)
                    o_acc[q2][db] = __builtin_amdgcn_mfma_f32_16x16x32_bf16(
                        va[k2][db], pb[k2], o_acc[q2][db], 0, 0, 0);
        }
    }

    // epilogue: q = l16 for every value at this lane -> shuffle-free normalize
    const int b = bh >> 4, h = bh & 15;
#pragma unroll
    for (int q2 = 0; q2 < 2; q2++) {
        float lr = l_part[q2];
        lr += __shfl_xor(lr, 16, 64);
        lr += __shfl_xor(lr, 32, 64);
        const float inv = 1.f / lr;
        const int grow = b * 2048 + q0 + w * 32 + q2 * 16 + l16;
        float s = 0.f, s2 = 0.f;
#pragma unroll
        for (int db = 0; db < 4; db++) {
            const float o0 = o_acc[q2][db][0] * inv, o1 = o_acc[q2][db][1] * inv;
            const float o2 = o_acc[q2][db][2] * inv, o3 = o_acc[q2][db][3] * inv;
            const ushort4 st = {f2bf(o0), f2bf(o1), f2bf(o2), f2bf(o3)};
            *reinterpret_cast<ushort4*>(
                &attn[(size_t)grow * 1024 + h * 64 + db * 16 + quad * 4]) = st;
            s  += (o0 + o1) + (o2 + o3);
            s2 += (o0 * o0 + o1 * o1) + (o2 * o2 + o3 * o3);
        }
        s  += __shfl_xor(s, 16, 64);  s  += __shfl_xor(s, 32, 64);
        s2 += __shfl_xor(s2, 16, 64); s2 += __shfl_xor(s2, 32, 64);
        if (quad == 0) part[(size_t)grow * 16 + h] = float2{s, s2};
    }
}

// ---------------- 128x128 MFMA GEMM core, double-buffered (for proj).
__device__ __forceinline__ void stage_tiles(const unsigned short* __restrict__ A,
                                            const unsigned short* __restrict__ Bt,
                                            int K, int m0, int n0, int k0,
                                            unsigned short* As, unsigned short* Bs,
                                            int w, int ls, int sg) {
#pragma unroll
    for (int i = 0; i < 4; i++) {
        const int r = w * 32 + i * 8 + ls;          // r&7 == ls
        const int g = (sg ^ ls) * 8;
        gll16(&A[(size_t)(m0 + r) * K + k0 + g], &As[(w * 32 + i * 8) * 64]);
        gll16(&Bt[(size_t)(n0 + r) * K + k0 + g], &Bs[(w * 32 + i * 8) * 64]);
    }
}

__device__ __forceinline__ void gemm128_core(const unsigned short* __restrict__ A,
                                             const unsigned short* __restrict__ Bt,
                                             int K, int m0, int n0,
                                             unsigned short* As, unsigned short* Bs,
                                             float4v acc[4][4]) {
    const int tid = threadIdx.x, lane = tid & 63, w = tid >> 6;
    const int wr = (w >> 1) * 64, wc = (w & 1) * 64;
    const int quad = lane >> 4, l16 = lane & 15;
    const int ls = lane >> 3, sg = lane & 7;
#pragma unroll
    for (int mi = 0; mi < 4; mi++)
#pragma unroll
        for (int ni = 0; ni < 4; ni++) acc[mi][ni] = float4v{0.f, 0.f, 0.f, 0.f};

    const int NS = K >> 6;
    stage_tiles(A, Bt, K, m0, n0, 0, As, Bs, w, ls, sg);
    for (int s = 0; s < NS; s++) {
        __syncthreads();
        const int cur = (s & 1) << 13;
        if (s + 1 < NS)
            stage_tiles(A, Bt, K, m0, n0, (s + 1) << 6,
                        As + (((s + 1) & 1) << 13), Bs + (((s + 1) & 1) << 13),
                        w, ls, sg);
        const unsigned short* Ac = As + cur;
        const unsigned short* Bc = Bs + cur;
#pragma unroll
        for (int ks = 0; ks < 2; ks++) {
            short8 af[4], bfr[4];
#pragma unroll
            for (int mi = 0; mi < 4; mi++) {
                const int r = wr + mi * 16 + l16;
                af[mi] = *reinterpret_cast<const short8*>(
                    &Ac[r * 64 + ((ks * 4 + quad) ^ (r & 7)) * 8]);
            }
#pragma unroll
            for (int ni = 0; ni < 4; ni++) {
                const int r = wc + ni * 16 + l16;
                bfr[ni] = *reinterpret_cast<const short8*>(
                    &Bc[r * 64 + ((ks * 4 + quad) ^ (r & 7)) * 8]);
            }
#pragma unroll
            for (int mi = 0; mi < 4; mi++)
#pragma unroll
                for (int ni = 0; ni < 4; ni++)
                    acc[mi][ni] = __builtin_amdgcn_mfma_f32_16x16x32_bf16(
                        af[mi], bfr[ni], acc[mi][ni], 0, 0, 0);
        }
    }
}

// ---------------- GEMM2: attn(bf16,raw) @ Wg^T, LN2 + rowstats fused in-kernel
__global__ __launch_bounds__(256) void gemm128_proj(const unsigned short* __restrict__ A,
                                                    const unsigned short* __restrict__ Bt,
                                                    const float2* __restrict__ part,
                                                    const float* __restrict__ u,
                                                    const float* __restrict__ w0,
                                                    const float* __restrict__ bias,
                                                    float* __restrict__ out) {
    __shared__ unsigned short As[2 * 128 * 64], Bs[2 * 128 * 64];
    __shared__ float2 rstat_s[128];
    const int m0 = blockIdx.y * 128, n0 = blockIdx.x * 128;
    {   // rowstats for this block's 128 rows: 2 threads/row, 8 heads each
        const int t = threadIdx.x, rloc = t >> 1, half = t & 1;
        const float4* p4 = reinterpret_cast<const float4*>(part);
        float s = 0.f, s2 = 0.f;
#pragma unroll
        for (int j = 0; j < 4; j++) {
            const float4 p = p4[(size_t)(m0 + rloc) * 8 + half * 4 + j];
            s += p.x + p.z; s2 += p.y + p.w;
        }
        s  += __shfl_xor(s, 1, 64);
        s2 += __shfl_xor(s2, 1, 64);
        if (!half) {
            const float mu = s * (1.f / 1024.f);
            const float rstd = rsqrtf(s2 * (1.f / 1024.f) - mu * mu + 1e-5f);
            rstat_s[rloc] = float2{rstd, mu * rstd};
        }
    }   // ordered before use by the core's internal __syncthreads()
    float4v acc[4][4];
    gemm128_core(A, Bt, 1024, m0, n0, As, Bs, acc);
    const int lane = threadIdx.x & 63, w = threadIdx.x >> 6;
    const int wr = (w >> 1) * 64, wc = (w & 1) * 64;
    const int quad = lane >> 4, l16 = lane & 15;
#pragma unroll
    for (int mi = 0; mi < 4; mi++) {
        const int rl0 = wr + mi * 16 + quad * 4;
        float2 rs[4];
#pragma unroll
        for (int r = 0; r < 4; r++) rs[r] = rstat_s[rl0 + r];
#pragma unroll
        for (int ni = 0; ni < 4; ni++) {
            const int col = n0 + wc + ni * 16 + l16;
            const float uu = u[col], ww = w0[col] + bias[col];
#pragma unroll
            for (int r = 0; r < 4; r++)
                out[(size_t)(m0 + rl0 + r) * 1024 + col] =
                    fmaf(rs[r].x, acc[mi][ni][r], ww - rs[r].y * uu);
        }
    }
}

extern "C" void kernel_launch(void* const* d_in, const int* in_sizes, int n_in,
                              void* d_out, int out_size, void* d_ws, size_t ws_size,
                              hipStream_t stream) {
    const float* x      = (const float*)d_in[0];
    const float* ln1_g  = (const float*)d_in[1];
    const float* ln1_b  = (const float*)d_in[2];
    const float* w_qk   = (const float*)d_in[3];
    const float* w_v    = (const float*)d_in[4];
    const float* ln2_g  = (const float*)d_in[5];
    const float* ln2_b  = (const float*)d_in[6];
    const float* w_proj = (const float*)d_in[7];
    const float* b_proj = (const float*)d_in[8];
    float* out = (float*)d_out;

    char* ws = (char*)d_ws;
    unsigned short* xn      = (unsigned short*)(ws + 0);         // 8MB  4096x1024 bf16
    unsigned short* wqkvT   = (unsigned short*)(ws + 8388608);   // 6MB  3072x1024 bf16
    unsigned short* wgT     = (unsigned short*)(ws + 14680064);  // 2MB  1024x1024 bf16 (g2-scaled w_proj^T)
    unsigned short* qbuf    = (unsigned short*)(ws + 16777216);  // 8MB  [32][2048][64]
    unsigned short* kbuf    = (unsigned short*)(ws + 25165824);  // 8MB  [32][2048][64]
    unsigned short* vTbuf   = (unsigned short*)(ws + 33554432);  // 8MB  [32][64][2048]
    unsigned short* attn    = (unsigned short*)(ws + 41943040);  // 8MB  4096x1024 bf16 (raw, pre-LN2)
    float2*         part    = (float2*)(ws + 50331648);          // 512KB [4096][16]
    float*          u       = (float*)(ws + 50888704);           // 4KB
    float*          w0      = (float*)(ws + 50892800);           // 4KB

    hipMemsetAsync(ws + 50888704, 0, 8192, stream);              // zero u + w0
    prep<<<8192, 256, 0, stream>>>(x, ln1_g, ln1_b, w_qk, w_v, w_proj, ln2_g, ln2_b,
                                   xn, wqkvT, wgT, u, w0);
    gemm256_qkv<<<dim3(12, 16), 512, 0, stream>>>(xn, wqkvT, qbuf, kbuf, vTbuf);
    flash_attn<<<dim3(16, 32), 256, 0, stream>>>(qbuf, kbuf, vTbuf, attn, part);
    gemm128_proj<<<dim3(8, 32), 256, 0, stream>>>(attn, wgT, part, u, w0, b_proj, out);
}

// Round 8
// 205.793 us; speedup vs baseline: 1.1177x; 1.1177x over previous
//
#include <hip/hip_runtime.h>
#include <hip/hip_bf16.h>

// B=2, N=2048, C=1024, H=16, hd=64, M=4096. bf16 MFMA path (threshold 2%).

typedef __attribute__((ext_vector_type(8))) short short8;
typedef __attribute__((ext_vector_type(4))) short short4v;
typedef __attribute__((ext_vector_type(4))) float float4v;
typedef __attribute__((ext_vector_type(4))) unsigned uint4v;

__device__ __forceinline__ unsigned short f2bf(float f) {   // RTNE
    unsigned u = __builtin_bit_cast(unsigned, f);
    return (unsigned short)((u + 0x7FFFu + ((u >> 16) & 1u)) >> 16);
}
// pack two f32 -> two bf16 (round-half-up) in one dword via v_perm
__device__ __forceinline__ unsigned packbf2(float lo, float hi) {
    return __builtin_amdgcn_perm(__builtin_bit_cast(unsigned, hi) + 0x8000u,
                                 __builtin_bit_cast(unsigned, lo) + 0x8000u,
                                 0x07060302u);
}
__device__ __forceinline__ void gll16(const unsigned short* g, unsigned short* l) {
    __builtin_amdgcn_global_load_lds(
        (const __attribute__((address_space(1))) unsigned int*)g,
        (__attribute__((address_space(3))) unsigned int*)l, 16, 0, 0);
}

// ---------------- prep: ln1 (blocks 0..4095) + weight transposes.
__global__ __launch_bounds__(256) void prep(
    const float* __restrict__ x, const float* __restrict__ g1, const float* __restrict__ b1,
    const float* __restrict__ w_qk, const float* __restrict__ w_v,
    const float* __restrict__ w_proj, const float* __restrict__ g2,
    const float* __restrict__ b2,
    unsigned short* __restrict__ xn, unsigned short* __restrict__ wqkvT,
    unsigned short* __restrict__ wgT, float* __restrict__ u, float* __restrict__ w0) {
    __shared__ float sh[32 * 33];
    const int bid = blockIdx.x, tid = threadIdx.x;
    if (bid < 4096) {                       // ---- LN1 row
        const float4 v = reinterpret_cast<const float4*>(x + (size_t)bid * 1024)[tid];
        float s  = v.x + v.y + v.z + v.w;
        float sq = v.x * v.x + v.y * v.y + v.z * v.z + v.w * v.w;
#pragma unroll
        for (int off = 32; off >= 1; off >>= 1) {
            s  += __shfl_xor(s, off, 64);
            sq += __shfl_xor(sq, off, 64);
        }
        const int w = tid >> 6, lane = tid & 63;
        if (lane == 0) { sh[w] = s; sh[4 + w] = sq; }
        __syncthreads();
        s  = sh[0] + sh[1] + sh[2] + sh[3];
        sq = sh[4] + sh[5] + sh[6] + sh[7];
        const float mu = s * (1.f / 1024.f);
        const float rstd = rsqrtf(sq * (1.f / 1024.f) - mu * mu + 1e-5f);
        const float4 gv = reinterpret_cast<const float4*>(g1)[tid];
        const float4 bv = reinterpret_cast<const float4*>(b1)[tid];
        ushort4 o;
        o.x = f2bf((v.x - mu) * rstd * gv.x + bv.x);
        o.y = f2bf((v.y - mu) * rstd * gv.y + bv.y);
        o.z = f2bf((v.z - mu) * rstd * gv.z + bv.z);
        o.w = f2bf((v.w - mu) * rstd * gv.w + bv.w);
        *reinterpret_cast<ushort4*>(&xn[(size_t)bid * 1024 + tid * 4]) = o;
    } else {                                // ---- transpose f32[1024][Cc] -> bf16[Cc][1024]
        const float* in; unsigned short* out; int Cc, bx, by; bool doU = false;
        if (bid < 6144)      { int t = bid - 4096; in = w_qk;   out = wqkvT;               Cc = 2048; bx = t & 63; by = t >> 6; }
        else if (bid < 7168) { int t = bid - 6144; in = w_v;    out = wqkvT + 2048 * 1024; Cc = 1024; bx = t & 31; by = t >> 5; }
        else                 { int t = bid - 7168; in = w_proj; out = wgT; doU = true;     Cc = 1024; bx = t & 31; by = t >> 5; }
        const int c0 = bx * 32, r0 = by * 32;
        const int tx = tid & 31, ty = tid >> 5;
#pragma unroll
        for (int i = 0; i < 32; i += 8)
            sh[(ty + i) * 33 + tx] = in[(size_t)(r0 + ty + i) * Cc + c0 + tx];
        __syncthreads();
        // out col = original row index c = r0+tx
        const float scale = doU ? g2[r0 + tx] : 1.f;
        const float b2v   = doU ? b2[r0 + tx] : 0.f;
#pragma unroll
        for (int i = 0; i < 32; i += 8) {
            const float raw = sh[tx * 33 + ty + i];
            const float sc  = raw * scale;
            out[(size_t)(c0 + ty + i) * 1024 + r0 + tx] = f2bf(sc);
            if (doU) {
                float pu = sc, pw = raw * b2v;    // per-c contributions for j=c0+ty+i
#pragma unroll
                for (int off = 1; off <= 16; off <<= 1) {   // reduce over tx (32 lanes)
                    pu += __shfl_xor(pu, off, 64);
                    pw += __shfl_xor(pw, off, 64);
                }
                if (tx == 0) {
                    atomicAdd(&u[c0 + ty + i], pu);
                    atomicAdd(&w0[c0 + ty + i], pw);
                }
            }
        }
    }
}

// ---------------- GEMM1: 256x256 tile, 512 threads, double-buffered.
__global__ __launch_bounds__(512) void gemm256_qkv(const unsigned short* __restrict__ A,
                                                   const unsigned short* __restrict__ Bt,
                                                   unsigned short* __restrict__ qb,
                                                   unsigned short* __restrict__ kb,
                                                   unsigned short* __restrict__ vT) {
    __shared__ unsigned short As[2 * 256 * 64], Bs[2 * 256 * 64];   // 128 KB
    const int tid = threadIdx.x, lane = tid & 63, w = tid >> 6;     // w 0..7
    const int wm = (w >> 2) * 128, wn = (w & 3) * 64;
    const int quad = lane >> 4, l16 = lane & 15;
    const int ls = lane >> 3, sg = lane & 7;
    const int m0 = blockIdx.y * 256, n0 = blockIdx.x * 256;

    float4v acc[8][4];
#pragma unroll
    for (int mi = 0; mi < 8; mi++)
#pragma unroll
        for (int ni = 0; ni < 4; ni++) acc[mi][ni] = float4v{0.f, 0.f, 0.f, 0.f};

    const int g = (sg ^ ls) * 8;
#pragma unroll 1
    for (int s = -1; s < 16; s++) {
        if (s >= 0) __syncthreads();
        if (s + 1 < 16) {                   // stage step s+1
            const int k0 = (s + 1) << 6, buf = ((s + 1) & 1) << 14;
            unsigned short* Ad = As + buf;
            unsigned short* Bd = Bs + buf;
#pragma unroll
            for (int i = 0; i < 4; i++) {
                const int r = w * 32 + i * 8 + ls;      // r&7 == ls
                gll16(&A[(size_t)(m0 + r) * 1024 + k0 + g], &Ad[(w * 32 + i * 8) * 64]);
                gll16(&Bt[(size_t)(n0 + r) * 1024 + k0 + g], &Bd[(w * 32 + i * 8) * 64]);
            }
        }
        if (s < 0) continue;
        const unsigned short* Ac = As + ((s & 1) << 14);
        const unsigned short* Bc = Bs + ((s & 1) << 14);
#pragma unroll
        for (int ks = 0; ks < 2; ks++) {
            short8 af[8], bfr[4];
#pragma unroll
            for (int mi = 0; mi < 8; mi++) {
                const int r = wm + mi * 16 + l16;
                af[mi] = *reinterpret_cast<const short8*>(
                    &Ac[r * 64 + ((ks * 4 + quad) ^ (r & 7)) * 8]);
            }
#pragma unroll
            for (int ni = 0; ni < 4; ni++) {
                const int r = wn + ni * 16 + l16;
                bfr[ni] = *reinterpret_cast<const short8*>(
                    &Bc[r * 64 + ((ks * 4 + quad) ^ (r & 7)) * 8]);
            }
#pragma unroll
            for (int mi = 0; mi < 8; mi++)
#pragma unroll
                for (int ni = 0; ni < 4; ni++)
                    acc[mi][ni] = __builtin_amdgcn_mfma_f32_16x16x32_bf16(
                        af[mi], bfr[ni], acc[mi][ni], 0, 0, 0);
        }
    }

    const float QSCALE = 0.125f * 1.4426950408889634f;  // hd^-0.5 * log2(e)
#pragma unroll
    for (int mi = 0; mi < 8; mi++) {
        const int row0 = m0 + wm + mi * 16 + quad * 4;
        const int b = row0 >> 11, nq = row0 & 2047;
#pragma unroll
        for (int ni = 0; ni < 4; ni++) {
            const int col = n0 + wn + ni * 16 + l16;
            if (col < 1024) {             // q: [bh][n][d]
                const int h = col >> 6, d = col & 63;
#pragma unroll
                for (int r = 0; r < 4; r++)
                    qb[(((size_t)b * 16 + h) * 2048 + nq + r) * 64 + d] =
                        f2bf(acc[mi][ni][r] * QSCALE);
            } else if (col < 2048) {      // k: [bh][n][d]
                const int c = col - 1024, h = c >> 6, d = c & 63;
#pragma unroll
                for (int r = 0; r < 4; r++)
                    kb[(((size_t)b * 16 + h) * 2048 + nq + r) * 64 + d] = f2bf(acc[mi][ni][r]);
            } else {                      // v^T: [bh][d][n], 4 consecutive keys -> 8B store
                const int c = col - 2048, h = c >> 6, d = c & 63;
                const short4v sv = {(short)f2bf(acc[mi][ni][0]), (short)f2bf(acc[mi][ni][1]),
                                    (short)f2bf(acc[mi][ni][2]), (short)f2bf(acc[mi][ni][3])};
                *reinterpret_cast<short4v*>(
                    &vT[(((size_t)b * 16 + h) * 64 + d) * 2048 + nq]) = sv;
            }
        }
    }
}

// ---------------- flash attention v6: full-rate PV (O^T = V^T P^T, P direct
// from registers via permuted-K S^T layout — validated R7) + V^T staged in
// LDS once per block via global_load_lds (R7's per-wave global V reads were
// 4x the L2 traffic — the regression cause). K and V both double-buffered,
// one barrier per tile. Q-tile 128, 256 thr, grid 512 = 2 blocks/CU.
__global__ __launch_bounds__(256) void flash_attn(const unsigned short* __restrict__ qbuf,
                                                  const unsigned short* __restrict__ kb,
                                                  const unsigned short* __restrict__ vT,
                                                  unsigned short* __restrict__ attn,
                                                  float2* __restrict__ part) {
    __shared__ unsigned short Ks[2][64 * 64];   // K tile, permuted rows, XOR-swizzled
    __shared__ unsigned short Vs[2][64 * 64];   // V^T tile [d][key], XOR-swizzled
    const int tid = threadIdx.x, lane = tid & 63, w = tid >> 6;   // w 0..3
    const int quad = lane >> 4, l16 = lane & 15;
    const int ls = lane >> 3, sg = lane & 7;
    const int q0 = blockIdx.x * 128, bh = blockIdx.y;
    const size_t nbase = (size_t)bh * 2048;

    // K staging source rows: phys row pr holds actual key ka(pr)
    // ka = [bit5][quad(2b)][cb&1][reg(2b)] from pr = [bit5][cb&1][quad][reg]
    int srow[2];
#pragma unroll
    for (int i = 0; i < 2; i++) {
        const int pr = w * 16 + i * 8 + ls;
        srow[i] = (pr & 32) | ((pr & 12) << 1) | ((pr & 16) >> 2) | (pr & 3);
    }
    const int sgran = (sg ^ ls) << 3;

    short8 bq[2][2];   // Q as B-operand for two 16-q subblocks (q = w*32+q2*16+l16)
#pragma unroll
    for (int q2 = 0; q2 < 2; q2++)
#pragma unroll
        for (int ks = 0; ks < 2; ks++)
            bq[q2][ks] = *reinterpret_cast<const short8*>(
                &qbuf[(nbase + q0 + w * 32 + q2 * 16 + l16) * 64 + ks * 32 + quad * 8]);

    float l_part[2] = {0.f, 0.f};
    float4v o_acc[2][4];   // o_acc[q2][db][reg]: d = db*16+quad*4+reg, q = l16
#pragma unroll
    for (int q2 = 0; q2 < 2; q2++)
#pragma unroll
        for (int db = 0; db < 4; db++) o_acc[q2][db] = float4v{0.f, 0.f, 0.f, 0.f};

    // stage tile 0 (K permuted; V rows d = w*16+i*8+ls, tile-row 128B)
#pragma unroll
    for (int i = 0; i < 2; i++) {
        gll16(&kb[(nbase + srow[i]) * 64 + sgran], &Ks[0][(w * 16 + i * 8) * 64]);
        gll16(&vT[((size_t)bh * 64 + w * 16 + i * 8 + ls) * 2048 + sgran],
              &Vs[0][(w * 16 + i * 8) * 64]);
    }

#pragma unroll 1
    for (int s = 0; s < 32; s++) {
        __syncthreads();                    // drains tile-s DMA
        if (s + 1 < 32) {                   // stage tile s+1 (drained next barrier)
            const int ktn = (s + 1) << 6, buf = (s + 1) & 1;
#pragma unroll
            for (int i = 0; i < 2; i++) {
                gll16(&kb[(nbase + ktn + srow[i]) * 64 + sgran],
                      &Ks[buf][(w * 16 + i * 8) * 64]);
                gll16(&vT[((size_t)bh * 64 + w * 16 + i * 8 + ls) * 2048 + ktn + sgran],
                      &Vs[buf][(w * 16 + i * 8) * 64]);
            }
        }
        const unsigned short* Kc = Ks[s & 1];
        const unsigned short* Vc = Vs[s & 1];

        short8 kf[2][4];
#pragma unroll
        for (int ks = 0; ks < 2; ks++)
#pragma unroll
            for (int cb = 0; cb < 4; cb++) {
                const int r = cb * 16 + l16;
                kf[ks][cb] = *reinterpret_cast<const short8*>(
                    &Kc[r * 64 + ((ks * 4 + quad) ^ (r & 7)) * 8]);
            }
        // V^T A-fragments from LDS: A[m=d=db*16+l16][k=key=k2*32+quad*8+j]
        short8 va[2][4];
#pragma unroll
        for (int k2 = 0; k2 < 2; k2++)
#pragma unroll
            for (int db = 0; db < 4; db++) {
                const int r = db * 16 + l16;
                va[k2][db] = *reinterpret_cast<const short8*>(
                    &Vc[r * 64 + ((k2 * 4 + quad) ^ (r & 7)) * 8]);
            }

#pragma unroll
        for (int q2 = 0; q2 < 2; q2++) {
            float4v s_acc[4];
#pragma unroll
            for (int cb = 0; cb < 4; cb++) s_acc[cb] = float4v{0.f, 0.f, 0.f, 0.f};
#pragma unroll
            for (int ks = 0; ks < 2; ks++)
#pragma unroll
                for (int cb = 0; cb < 4; cb++)
                    s_acc[cb] = __builtin_amdgcn_mfma_f32_16x16x32_bf16(
                        kf[ks][cb], bq[q2][ks], s_acc[cb], 0, 0, 0);

            // fixed-max softmax: p = 2^s (s hard-bounded, O/l cancels).
            // pack P^T B-operand: k = quad*8 + (cb&1)*4 + reg
            float ls2 = 0.f;
            short8 pb[2];
#pragma unroll
            for (int k2 = 0; k2 < 2; k2++) {
                float p[8];
#pragma unroll
                for (int cc = 0; cc < 2; cc++)
#pragma unroll
                    for (int r = 0; r < 4; r++) {
                        const float pv = __builtin_amdgcn_exp2f(s_acc[k2 * 2 + cc][r]);
                        p[cc * 4 + r] = pv;
                        ls2 += pv;
                    }
                uint4v pd;
                pd.x = packbf2(p[0], p[1]); pd.y = packbf2(p[2], p[3]);
                pd.z = packbf2(p[4], p[5]); pd.w = packbf2(p[6], p[7]);
                pb[k2] = __builtin_bit_cast(short8, pd);
            }
            l_part[q2] += ls2;
#pragma unroll
            for (int k2 = 0; k2 < 2; k2++)
#pragma unroll
                for (int db = 0; db < 4; db++)
                    o_acc[q2][db] = __builtin_amdgcn_mfma_f32_16x16x32_bf16(
                        va[k2][db], pb[k2], o_acc[q2][db], 0, 0, 0);
        }
    }

    // epilogue: q = l16 for every value at this lane -> shuffle-free normalize
    const int b = bh >> 4, h = bh & 15;
#pragma unroll
    for (int q2 = 0; q2 < 2; q2++) {
        float lr = l_part[q2];
        lr += __shfl_xor(lr, 16, 64);
        lr += __shfl_xor(lr, 32, 64);
        const float inv = 1.f / lr;
        const int grow = b * 2048 + q0 + w * 32 + q2 * 16 + l16;
        float s = 0.f, s2 = 0.f;
#pragma unroll
        for (int db = 0; db < 4; db++) {
            const float o0 = o_acc[q2][db][0] * inv, o1 = o_acc[q2][db][1] * inv;
            const float o2 = o_acc[q2][db][2] * inv, o3 = o_acc[q2][db][3] * inv;
            const ushort4 st = {f2bf(o0), f2bf(o1), f2bf(o2), f2bf(o3)};
            *reinterpret_cast<ushort4*>(
                &attn[(size_t)grow * 1024 + h * 64 + db * 16 + quad * 4]) = st;
            s  += (o0 + o1) + (o2 + o3);
            s2 += (o0 * o0 + o1 * o1) + (o2 * o2 + o3 * o3);
        }
        s  += __shfl_xor(s, 16, 64);  s  += __shfl_xor(s, 32, 64);
        s2 += __shfl_xor(s2, 16, 64); s2 += __shfl_xor(s2, 32, 64);
        if (quad == 0) part[(size_t)grow * 16 + h] = float2{s, s2};
    }
}

// ---------------- 128x128 MFMA GEMM core, double-buffered (for proj).
__device__ __forceinline__ void stage_tiles(const unsigned short* __restrict__ A,
                                            const unsigned short* __restrict__ Bt,
                                            int K, int m0, int n0, int k0,
                                            unsigned short* As, unsigned short* Bs,
                                            int w, int ls, int sg) {
#pragma unroll
    for (int i = 0; i < 4; i++) {
        const int r = w * 32 + i * 8 + ls;          // r&7 == ls
        const int g = (sg ^ ls) * 8;
        gll16(&A[(size_t)(m0 + r) * K + k0 + g], &As[(w * 32 + i * 8) * 64]);
        gll16(&Bt[(size_t)(n0 + r) * K + k0 + g], &Bs[(w * 32 + i * 8) * 64]);
    }
}

__device__ __forceinline__ void gemm128_core(const unsigned short* __restrict__ A,
                                             const unsigned short* __restrict__ Bt,
                                             int K, int m0, int n0,
                                             unsigned short* As, unsigned short* Bs,
                                             float4v acc[4][4]) {
    const int tid = threadIdx.x, lane = tid & 63, w = tid >> 6;
    const int wr = (w >> 1) * 64, wc = (w & 1) * 64;
    const int quad = lane >> 4, l16 = lane & 15;
    const int ls = lane >> 3, sg = lane & 7;
#pragma unroll
    for (int mi = 0; mi < 4; mi++)
#pragma unroll
        for (int ni = 0; ni < 4; ni++) acc[mi][ni] = float4v{0.f, 0.f, 0.f, 0.f};

    const int NS = K >> 6;
    stage_tiles(A, Bt, K, m0, n0, 0, As, Bs, w, ls, sg);
    for (int s = 0; s < NS; s++) {
        __syncthreads();
        const int cur = (s & 1) << 13;
        if (s + 1 < NS)
            stage_tiles(A, Bt, K, m0, n0, (s + 1) << 6,
                        As + (((s + 1) & 1) << 13), Bs + (((s + 1) & 1) << 13),
                        w, ls, sg);
        const unsigned short* Ac = As + cur;
        const unsigned short* Bc = Bs + cur;
#pragma unroll
        for (int ks = 0; ks < 2; ks++) {
            short8 af[4], bfr[4];
#pragma unroll
            for (int mi = 0; mi < 4; mi++) {
                const int r = wr + mi * 16 + l16;
                af[mi] = *reinterpret_cast<const short8*>(
                    &Ac[r * 64 + ((ks * 4 + quad) ^ (r & 7)) * 8]);
            }
#pragma unroll
            for (int ni = 0; ni < 4; ni++) {
                const int r = wc + ni * 16 + l16;
                bfr[ni] = *reinterpret_cast<const short8*>(
                    &Bc[r * 64 + ((ks * 4 + quad) ^ (r & 7)) * 8]);
            }
#pragma unroll
            for (int mi = 0; mi < 4; mi++)
#pragma unroll
                for (int ni = 0; ni < 4; ni++)
                    acc[mi][ni] = __builtin_amdgcn_mfma_f32_16x16x32_bf16(
                        af[mi], bfr[ni], acc[mi][ni], 0, 0, 0);
        }
    }
}

// ---------------- GEMM2: attn(bf16,raw) @ Wg^T, LN2 + rowstats fused in-kernel
__global__ __launch_bounds__(256) void gemm128_proj(const unsigned short* __restrict__ A,
                                                    const unsigned short* __restrict__ Bt,
                                                    const float2* __restrict__ part,
                                                    const float* __restrict__ u,
                                                    const float* __restrict__ w0,
                                                    const float* __restrict__ bias,
                                                    float* __restrict__ out) {
    __shared__ unsigned short As[2 * 128 * 64], Bs[2 * 128 * 64];
    __shared__ float2 rstat_s[128];
    const int m0 = blockIdx.y * 128, n0 = blockIdx.x * 128;
    {   // rowstats for this block's 128 rows: 2 threads/row, 8 heads each
        const int t = threadIdx.x, rloc = t >> 1, half = t & 1;
        const float4* p4 = reinterpret_cast<const float4*>(part);
        float s = 0.f, s2 = 0.f;
#pragma unroll
        for (int j = 0; j < 4; j++) {
            const float4 p = p4[(size_t)(m0 + rloc) * 8 + half * 4 + j];
            s += p.x + p.z; s2 += p.y + p.w;
        }
        s  += __shfl_xor(s, 1, 64);
        s2 += __shfl_xor(s2, 1, 64);
        if (!half) {
            const float mu = s * (1.f / 1024.f);
            const float rstd = rsqrtf(s2 * (1.f / 1024.f) - mu * mu + 1e-5f);
            rstat_s[rloc] = float2{rstd, mu * rstd};
        }
    }   // ordered before use by the core's internal __syncthreads()
    float4v acc[4][4];
    gemm128_core(A, Bt, 1024, m0, n0, As, Bs, acc);
    const int lane = threadIdx.x & 63, w = threadIdx.x >> 6;
    const int wr = (w >> 1) * 64, wc = (w & 1) * 64;
    const int quad = lane >> 4, l16 = lane & 15;
#pragma unroll
    for (int mi = 0; mi < 4; mi++) {
        const int rl0 = wr + mi * 16 + quad * 4;
        float2 rs[4];
#pragma unroll
        for (int r = 0; r < 4; r++) rs[r] = rstat_s[rl0 + r];
#pragma unroll
        for (int ni = 0; ni < 4; ni++) {
            const int col = n0 + wc + ni * 16 + l16;
            const float uu = u[col], ww = w0[col] + bias[col];
#pragma unroll
            for (int r = 0; r < 4; r++)
                out[(size_t)(m0 + rl0 + r) * 1024 + col] =
                    fmaf(rs[r].x, acc[mi][ni][r], ww - rs[r].y * uu);
        }
    }
}

extern "C" void kernel_launch(void* const* d_in, const int* in_sizes, int n_in,
                              void* d_out, int out_size, void* d_ws, size_t ws_size,
                              hipStream_t stream) {
    const float* x      = (const float*)d_in[0];
    const float* ln1_g  = (const float*)d_in[1];
    const float* ln1_b  = (const float*)d_in[2];
    const float* w_qk   = (const float*)d_in[3];
    const float* w_v    = (const float*)d_in[4];
    const float* ln2_g  = (const float*)d_in[5];
    const float* ln2_b  = (const float*)d_in[6];
    const float* w_proj = (const float*)d_in[7];
    const float* b_proj = (const float*)d_in[8];
    float* out = (float*)d_out;

    char* ws = (char*)d_ws;
    unsigned short* xn      = (unsigned short*)(ws + 0);         // 8MB  4096x1024 bf16
    unsigned short* wqkvT   = (unsigned short*)(ws + 8388608);   // 6MB  3072x1024 bf16
    unsigned short* wgT     = (unsigned short*)(ws + 14680064);  // 2MB  1024x1024 bf16 (g2-scaled w_proj^T)
    unsigned short* qbuf    = (unsigned short*)(ws + 16777216);  // 8MB  [32][2048][64]
    unsigned short* kbuf    = (unsigned short*)(ws + 25165824);  // 8MB  [32][2048][64]
    unsigned short* vTbuf   = (unsigned short*)(ws + 33554432);  // 8MB  [32][64][2048]
    unsigned short* attn    = (unsigned short*)(ws + 41943040);  // 8MB  4096x1024 bf16 (raw, pre-LN2)
    float2*         part    = (float2*)(ws + 50331648);          // 512KB [4096][16]
    float*          u       = (float*)(ws + 50888704);           // 4KB
    float*          w0      = (float*)(ws + 50892800);           // 4KB

    hipMemsetAsync(ws + 50888704, 0, 8192, stream);              // zero u + w0
    prep<<<8192, 256, 0, stream>>>(x, ln1_g, ln1_b, w_qk, w_v, w_proj, ln2_g, ln2_b,
                                   xn, wqkvT, wgT, u, w0);
    gemm256_qkv<<<dim3(12, 16), 512, 0, stream>>>(xn, wqkvT, qbuf, kbuf, vTbuf);
    flash_attn<<<dim3(16, 32), 256, 0, stream>>>(qbuf, kbuf, vTbuf, attn, part);
    gemm128_proj<<<dim3(8, 32), 256, 0, stream>>>(attn, wgT, part, u, w0, b_proj, out);
}

// Round 9
// 202.002 us; speedup vs baseline: 1.1387x; 1.0188x over previous
//
#include <hip/hip_runtime.h>
#include <hip/hip_bf16.h>

// B=2, N=2048, C=1024, H=16, hd=64, M=4096. bf16 MFMA path (threshold 2%).

typedef __attribute__((ext_vector_type(8))) short short8;
typedef __attribute__((ext_vector_type(4))) short short4v;
typedef __attribute__((ext_vector_type(4))) float float4v;
typedef __attribute__((ext_vector_type(4))) unsigned uint4v;

__device__ __forceinline__ unsigned short f2bf(float f) {   // RTNE
    unsigned u = __builtin_bit_cast(unsigned, f);
    return (unsigned short)((u + 0x7FFFu + ((u >> 16) & 1u)) >> 16);
}
// pack two f32 -> two bf16 (round-half-up) in one dword via v_perm
__device__ __forceinline__ unsigned packbf2(float lo, float hi) {
    return __builtin_amdgcn_perm(__builtin_bit_cast(unsigned, hi) + 0x8000u,
                                 __builtin_bit_cast(unsigned, lo) + 0x8000u,
                                 0x07060302u);
}
__device__ __forceinline__ void gll16(const unsigned short* g, unsigned short* l) {
    __builtin_amdgcn_global_load_lds(
        (const __attribute__((address_space(1))) unsigned int*)g,
        (__attribute__((address_space(3))) unsigned int*)l, 16, 0, 0);
}

// ---------------- prep: ln1 (blocks 0..4095) + weight transposes.
__global__ __launch_bounds__(256) void prep(
    const float* __restrict__ x, const float* __restrict__ g1, const float* __restrict__ b1,
    const float* __restrict__ w_qk, const float* __restrict__ w_v,
    const float* __restrict__ w_proj, const float* __restrict__ g2,
    const float* __restrict__ b2,
    unsigned short* __restrict__ xn, unsigned short* __restrict__ wqkvT,
    unsigned short* __restrict__ wgT, float* __restrict__ u, float* __restrict__ w0) {
    __shared__ float sh[32 * 33];
    const int bid = blockIdx.x, tid = threadIdx.x;
    if (bid < 4096) {                       // ---- LN1 row
        const float4 v = reinterpret_cast<const float4*>(x + (size_t)bid * 1024)[tid];
        float s  = v.x + v.y + v.z + v.w;
        float sq = v.x * v.x + v.y * v.y + v.z * v.z + v.w * v.w;
#pragma unroll
        for (int off = 32; off >= 1; off >>= 1) {
            s  += __shfl_xor(s, off, 64);
            sq += __shfl_xor(sq, off, 64);
        }
        const int w = tid >> 6, lane = tid & 63;
        if (lane == 0) { sh[w] = s; sh[4 + w] = sq; }
        __syncthreads();
        s  = sh[0] + sh[1] + sh[2] + sh[3];
        sq = sh[4] + sh[5] + sh[6] + sh[7];
        const float mu = s * (1.f / 1024.f);
        const float rstd = rsqrtf(sq * (1.f / 1024.f) - mu * mu + 1e-5f);
        const float4 gv = reinterpret_cast<const float4*>(g1)[tid];
        const float4 bv = reinterpret_cast<const float4*>(b1)[tid];
        ushort4 o;
        o.x = f2bf((v.x - mu) * rstd * gv.x + bv.x);
        o.y = f2bf((v.y - mu) * rstd * gv.y + bv.y);
        o.z = f2bf((v.z - mu) * rstd * gv.z + bv.z);
        o.w = f2bf((v.w - mu) * rstd * gv.w + bv.w);
        *reinterpret_cast<ushort4*>(&xn[(size_t)bid * 1024 + tid * 4]) = o;
    } else {                                // ---- transpose f32[1024][Cc] -> bf16[Cc][1024]
        const float* in; unsigned short* out; int Cc, bx, by; bool doU = false;
        if (bid < 6144)      { int t = bid - 4096; in = w_qk;   out = wqkvT;               Cc = 2048; bx = t & 63; by = t >> 6; }
        else if (bid < 7168) { int t = bid - 6144; in = w_v;    out = wqkvT + 2048 * 1024; Cc = 1024; bx = t & 31; by = t >> 5; }
        else                 { int t = bid - 7168; in = w_proj; out = wgT; doU = true;     Cc = 1024; bx = t & 31; by = t >> 5; }
        const int c0 = bx * 32, r0 = by * 32;
        const int tx = tid & 31, ty = tid >> 5;
#pragma unroll
        for (int i = 0; i < 32; i += 8)
            sh[(ty + i) * 33 + tx] = in[(size_t)(r0 + ty + i) * Cc + c0 + tx];
        __syncthreads();
        // out col = original row index c = r0+tx
        const float scale = doU ? g2[r0 + tx] : 1.f;
        const float b2v   = doU ? b2[r0 + tx] : 0.f;
#pragma unroll
        for (int i = 0; i < 32; i += 8) {
            const float raw = sh[tx * 33 + ty + i];
            const float sc  = raw * scale;
            out[(size_t)(c0 + ty + i) * 1024 + r0 + tx] = f2bf(sc);
            if (doU) {
                float pu = sc, pw = raw * b2v;    // per-c contributions for j=c0+ty+i
#pragma unroll
                for (int off = 1; off <= 16; off <<= 1) {   // reduce over tx (32 lanes)
                    pu += __shfl_xor(pu, off, 64);
                    pw += __shfl_xor(pw, off, 64);
                }
                if (tx == 0) {
                    atomicAdd(&u[c0 + ty + i], pu);
                    atomicAdd(&w0[c0 + ty + i], pw);
                }
            }
        }
    }
}

// ---------------- GEMM1: 256x256 tile, 512 threads, double-buffered.
__global__ __launch_bounds__(512) void gemm256_qkv(const unsigned short* __restrict__ A,
                                                   const unsigned short* __restrict__ Bt,
                                                   unsigned short* __restrict__ qb,
                                                   unsigned short* __restrict__ kb,
                                                   unsigned short* __restrict__ vT) {
    __shared__ unsigned short As[2 * 256 * 64], Bs[2 * 256 * 64];   // 128 KB
    const int tid = threadIdx.x, lane = tid & 63, w = tid >> 6;     // w 0..7
    const int wm = (w >> 2) * 128, wn = (w & 3) * 64;
    const int quad = lane >> 4, l16 = lane & 15;
    const int ls = lane >> 3, sg = lane & 7;
    const int m0 = blockIdx.y * 256, n0 = blockIdx.x * 256;

    float4v acc[8][4];
#pragma unroll
    for (int mi = 0; mi < 8; mi++)
#pragma unroll
        for (int ni = 0; ni < 4; ni++) acc[mi][ni] = float4v{0.f, 0.f, 0.f, 0.f};

    const int g = (sg ^ ls) * 8;
#pragma unroll 1
    for (int s = -1; s < 16; s++) {
        if (s >= 0) __syncthreads();
        if (s + 1 < 16) {                   // stage step s+1
            const int k0 = (s + 1) << 6, buf = ((s + 1) & 1) << 14;
            unsigned short* Ad = As + buf;
            unsigned short* Bd = Bs + buf;
#pragma unroll
            for (int i = 0; i < 4; i++) {
                const int r = w * 32 + i * 8 + ls;      // r&7 == ls
                gll16(&A[(size_t)(m0 + r) * 1024 + k0 + g], &Ad[(w * 32 + i * 8) * 64]);
                gll16(&Bt[(size_t)(n0 + r) * 1024 + k0 + g], &Bd[(w * 32 + i * 8) * 64]);
            }
        }
        if (s < 0) continue;
        const unsigned short* Ac = As + ((s & 1) << 14);
        const unsigned short* Bc = Bs + ((s & 1) << 14);
#pragma unroll
        for (int ks = 0; ks < 2; ks++) {
            short8 af[8], bfr[4];
#pragma unroll
            for (int mi = 0; mi < 8; mi++) {
                const int r = wm + mi * 16 + l16;
                af[mi] = *reinterpret_cast<const short8*>(
                    &Ac[r * 64 + ((ks * 4 + quad) ^ (r & 7)) * 8]);
            }
#pragma unroll
            for (int ni = 0; ni < 4; ni++) {
                const int r = wn + ni * 16 + l16;
                bfr[ni] = *reinterpret_cast<const short8*>(
                    &Bc[r * 64 + ((ks * 4 + quad) ^ (r & 7)) * 8]);
            }
#pragma unroll
            for (int mi = 0; mi < 8; mi++)
#pragma unroll
                for (int ni = 0; ni < 4; ni++)
                    acc[mi][ni] = __builtin_amdgcn_mfma_f32_16x16x32_bf16(
                        af[mi], bfr[ni], acc[mi][ni], 0, 0, 0);
        }
    }

    const float QSCALE = 0.125f * 1.4426950408889634f;  // hd^-0.5 * log2(e)
#pragma unroll
    for (int mi = 0; mi < 8; mi++) {
        const int row0 = m0 + wm + mi * 16 + quad * 4;
        const int b = row0 >> 11, nq = row0 & 2047;
#pragma unroll
        for (int ni = 0; ni < 4; ni++) {
            const int col = n0 + wn + ni * 16 + l16;
            if (col < 1024) {             // q: [bh][n][d]
                const int h = col >> 6, d = col & 63;
#pragma unroll
                for (int r = 0; r < 4; r++)
                    qb[(((size_t)b * 16 + h) * 2048 + nq + r) * 64 + d] =
                        f2bf(acc[mi][ni][r] * QSCALE);
            } else if (col < 2048) {      // k: [bh][n][d]
                const int c = col - 1024, h = c >> 6, d = c & 63;
#pragma unroll
                for (int r = 0; r < 4; r++)
                    kb[(((size_t)b * 16 + h) * 2048 + nq + r) * 64 + d] = f2bf(acc[mi][ni][r]);
            } else {                      // v^T: [bh][d][n], 4 consecutive keys -> 8B store
                const int c = col - 2048, h = c >> 6, d = c & 63;
                const short4v sv = {(short)f2bf(acc[mi][ni][0]), (short)f2bf(acc[mi][ni][1]),
                                    (short)f2bf(acc[mi][ni][2]), (short)f2bf(acc[mi][ni][3])};
                *reinterpret_cast<short4v*>(
                    &vT[(((size_t)b * 16 + h) * 64 + d) * 2048 + nq]) = sv;
            }
        }
    }
}

// ---------------- flash attention v7: v6 dataflow (full-rate reg-P PV,
// permuted-K S^T) with BK=128 per barrier (two 64-key subtiles per drain
// window) — halves the barrier-alignment stalls that serialized the
// VALU/MFMA/LDS pipes in v6 (pipes summed to ~4578 cyc/tile vs 3750 wall).
// LDS 64 KB dbuf keeps 2 blocks/CU. Q-tile 128, 256 thr, grid 512.
__global__ __launch_bounds__(256) void flash_attn(const unsigned short* __restrict__ qbuf,
                                                  const unsigned short* __restrict__ kb,
                                                  const unsigned short* __restrict__ vT,
                                                  unsigned short* __restrict__ attn,
                                                  float2* __restrict__ part) {
    __shared__ unsigned short Ks[2][2][64 * 64];   // [buf][subtile][key][d], permuted+swizzled
    __shared__ unsigned short Vs[2][2][64 * 64];   // [buf][subtile][d][key], swizzled
    const int tid = threadIdx.x, lane = tid & 63, w = tid >> 6;   // w 0..3
    const int quad = lane >> 4, l16 = lane & 15;
    const int ls = lane >> 3, sg = lane & 7;
    const int q0 = blockIdx.x * 128, bh = blockIdx.y;
    const size_t nbase = (size_t)bh * 2048;

    // K staging source rows: phys row pr holds actual key ka(pr)
    // ka = [bit5][quad(2b)][cb&1][reg(2b)] from pr = [bit5][cb&1][quad][reg]
    int srow[2];
#pragma unroll
    for (int i = 0; i < 2; i++) {
        const int pr = w * 16 + i * 8 + ls;
        srow[i] = (pr & 32) | ((pr & 12) << 1) | ((pr & 16) >> 2) | (pr & 3);
    }
    const int sgran = (sg ^ ls) << 3;

    short8 bq[2][2];   // Q as B-operand for two 16-q subblocks (q = w*32+q2*16+l16)
#pragma unroll
    for (int q2 = 0; q2 < 2; q2++)
#pragma unroll
        for (int ks = 0; ks < 2; ks++)
            bq[q2][ks] = *reinterpret_cast<const short8*>(
                &qbuf[(nbase + q0 + w * 32 + q2 * 16 + l16) * 64 + ks * 32 + quad * 8]);

    float l_part[2] = {0.f, 0.f};
    float4v o_acc[2][4];   // o_acc[q2][db][reg]: d = db*16+quad*4+reg, q = l16
#pragma unroll
    for (int q2 = 0; q2 < 2; q2++)
#pragma unroll
        for (int db = 0; db < 4; db++) o_acc[q2][db] = float4v{0.f, 0.f, 0.f, 0.f};

    // stage super-tile 0 (two 64-key subtiles)
#pragma unroll
    for (int t = 0; t < 2; t++)
#pragma unroll
        for (int i = 0; i < 2; i++) {
            gll16(&kb[(nbase + t * 64 + srow[i]) * 64 + sgran],
                  &Ks[0][t][(w * 16 + i * 8) * 64]);
            gll16(&vT[((size_t)bh * 64 + w * 16 + i * 8 + ls) * 2048 + t * 64 + sgran],
                  &Vs[0][t][(w * 16 + i * 8) * 64]);
        }

#pragma unroll 1
    for (int s = 0; s < 16; s++) {
        __syncthreads();                    // drains super-tile s DMA
        if (s + 1 < 16) {                   // stage super-tile s+1
            const int ktn = (s + 1) << 7, buf = (s + 1) & 1;
#pragma unroll
            for (int t = 0; t < 2; t++)
#pragma unroll
                for (int i = 0; i < 2; i++) {
                    gll16(&kb[(nbase + ktn + t * 64 + srow[i]) * 64 + sgran],
                          &Ks[buf][t][(w * 16 + i * 8) * 64]);
                    gll16(&vT[((size_t)bh * 64 + w * 16 + i * 8 + ls) * 2048 + ktn + t * 64 + sgran],
                          &Vs[buf][t][(w * 16 + i * 8) * 64]);
                }
        }
#pragma unroll
        for (int t = 0; t < 2; t++) {
            const unsigned short* Kc = Ks[s & 1][t];
            const unsigned short* Vc = Vs[s & 1][t];

            short8 kf[2][4];
#pragma unroll
            for (int ks = 0; ks < 2; ks++)
#pragma unroll
                for (int cb = 0; cb < 4; cb++) {
                    const int r = cb * 16 + l16;
                    kf[ks][cb] = *reinterpret_cast<const short8*>(
                        &Kc[r * 64 + ((ks * 4 + quad) ^ (r & 7)) * 8]);
                }
            short8 va[2][4];   // A[m=d=db*16+l16][k=key=k2*32+quad*8+j]
#pragma unroll
            for (int k2 = 0; k2 < 2; k2++)
#pragma unroll
                for (int db = 0; db < 4; db++) {
                    const int r = db * 16 + l16;
                    va[k2][db] = *reinterpret_cast<const short8*>(
                        &Vc[r * 64 + ((k2 * 4 + quad) ^ (r & 7)) * 8]);
                }

#pragma unroll
            for (int q2 = 0; q2 < 2; q2++) {
                float4v s_acc[4];
#pragma unroll
                for (int cb = 0; cb < 4; cb++) s_acc[cb] = float4v{0.f, 0.f, 0.f, 0.f};
#pragma unroll
                for (int ks = 0; ks < 2; ks++)
#pragma unroll
                    for (int cb = 0; cb < 4; cb++)
                        s_acc[cb] = __builtin_amdgcn_mfma_f32_16x16x32_bf16(
                            kf[ks][cb], bq[q2][ks], s_acc[cb], 0, 0, 0);

                // fixed-max softmax: p = 2^s (hard-bounded, O/l cancels).
                // pack P^T B-operand: k = quad*8 + (cb&1)*4 + reg
                float ls2 = 0.f;
                short8 pb[2];
#pragma unroll
                for (int k2 = 0; k2 < 2; k2++) {
                    float p[8];
#pragma unroll
                    for (int cc = 0; cc < 2; cc++)
#pragma unroll
                        for (int r = 0; r < 4; r++)
                            p[cc * 4 + r] = __builtin_amdgcn_exp2f(s_acc[k2 * 2 + cc][r]);
                    ls2 += ((p[0] + p[1]) + (p[2] + p[3])) +
                           ((p[4] + p[5]) + (p[6] + p[7]));   // tree, short dep chain
                    uint4v pd;
                    pd.x = packbf2(p[0], p[1]); pd.y = packbf2(p[2], p[3]);
                    pd.z = packbf2(p[4], p[5]); pd.w = packbf2(p[6], p[7]);
                    pb[k2] = __builtin_bit_cast(short8, pd);
                }
                l_part[q2] += ls2;
#pragma unroll
                for (int k2 = 0; k2 < 2; k2++)
#pragma unroll
                    for (int db = 0; db < 4; db++)
                        o_acc[q2][db] = __builtin_amdgcn_mfma_f32_16x16x32_bf16(
                            va[k2][db], pb[k2], o_acc[q2][db], 0, 0, 0);
            }
        }
    }

    // epilogue: q = l16 for every value at this lane -> shuffle-free normalize
    const int b = bh >> 4, h = bh & 15;
#pragma unroll
    for (int q2 = 0; q2 < 2; q2++) {
        float lr = l_part[q2];
        lr += __shfl_xor(lr, 16, 64);
        lr += __shfl_xor(lr, 32, 64);
        const float inv = 1.f / lr;
        const int grow = b * 2048 + q0 + w * 32 + q2 * 16 + l16;
        float s = 0.f, s2 = 0.f;
#pragma unroll
        for (int db = 0; db < 4; db++) {
            const float o0 = o_acc[q2][db][0] * inv, o1 = o_acc[q2][db][1] * inv;
            const float o2 = o_acc[q2][db][2] * inv, o3 = o_acc[q2][db][3] * inv;
            const ushort4 st = {f2bf(o0), f2bf(o1), f2bf(o2), f2bf(o3)};
            *reinterpret_cast<ushort4*>(
                &attn[(size_t)grow * 1024 + h * 64 + db * 16 + quad * 4]) = st;
            s  += (o0 + o1) + (o2 + o3);
            s2 += (o0 * o0 + o1 * o1) + (o2 * o2 + o3 * o3);
        }
        s  += __shfl_xor(s, 16, 64);  s  += __shfl_xor(s, 32, 64);
        s2 += __shfl_xor(s2, 16, 64); s2 += __shfl_xor(s2, 32, 64);
        if (quad == 0) part[(size_t)grow * 16 + h] = float2{s, s2};
    }
}

// ---------------- GEMM2: attn(bf16,raw) @ Wg^T, LN2 + rowstats fused.
// Tile 128(m) x 64(n) -> grid 512 = 2 blocks/CU (was 256 = 1/CU, the R6
// disease). Per wave/step: 4 af + 8 bfr LDS b128 (was 18). B-band 256 KB
// stays L2-resident across the 32 m-blocks that re-read it.
__global__ __launch_bounds__(256) void gemm_proj(const unsigned short* __restrict__ A,
                                                 const unsigned short* __restrict__ Bt,
                                                 const float2* __restrict__ part,
                                                 const float* __restrict__ u,
                                                 const float* __restrict__ w0,
                                                 const float* __restrict__ bias,
                                                 float* __restrict__ out) {
    __shared__ unsigned short As[2 * 128 * 64];   // 32 KB
    __shared__ unsigned short Bs[2 * 64 * 64];    // 16 KB
    __shared__ float2 rstat_s[128];
    const int tid = threadIdx.x, lane = tid & 63, w = tid >> 6;
    const int quad = lane >> 4, l16 = lane & 15;
    const int ls = lane >> 3, sg = lane & 7;
    const int m0 = blockIdx.y * 128, n0 = blockIdx.x * 64;
    {   // rowstats for this block's 128 rows: 2 threads/row, 8 heads each
        const int rloc = tid >> 1, half = tid & 1;
        const float4* p4 = reinterpret_cast<const float4*>(part);
        float s = 0.f, s2 = 0.f;
#pragma unroll
        for (int j = 0; j < 4; j++) {
            const float4 p = p4[(size_t)(m0 + rloc) * 8 + half * 4 + j];
            s += p.x + p.z; s2 += p.y + p.w;
        }
        s  += __shfl_xor(s, 1, 64);
        s2 += __shfl_xor(s2, 1, 64);
        if (!half) {
            const float mu = s * (1.f / 1024.f);
            const float rstd = rsqrtf(s2 * (1.f / 1024.f) - mu * mu + 1e-5f);
            rstat_s[rloc] = float2{rstd, mu * rstd};
        }
    }   // ordered before use by the K-loop's first __syncthreads()

    float4v acc[2][4];
#pragma unroll
    for (int mi = 0; mi < 2; mi++)
#pragma unroll
        for (int ni = 0; ni < 4; ni++) acc[mi][ni] = float4v{0.f, 0.f, 0.f, 0.f};

    const int g = (sg ^ ls) * 8;
    // stage step 0
#pragma unroll
    for (int i = 0; i < 4; i++)
        gll16(&A[(size_t)(m0 + w * 32 + i * 8 + ls) * 1024 + g], &As[(w * 32 + i * 8) * 64]);
#pragma unroll
    for (int i = 0; i < 2; i++)
        gll16(&Bt[(size_t)(n0 + w * 16 + i * 8 + ls) * 1024 + g], &Bs[(w * 16 + i * 8) * 64]);

#pragma unroll 1
    for (int s = 0; s < 16; s++) {
        __syncthreads();
        if (s + 1 < 16) {
            const int k0 = (s + 1) << 6;
            unsigned short* Ad = As + (((s + 1) & 1) << 13);
            unsigned short* Bd = Bs + (((s + 1) & 1) << 12);
#pragma unroll
            for (int i = 0; i < 4; i++)
                gll16(&A[(size_t)(m0 + w * 32 + i * 8 + ls) * 1024 + k0 + g],
                      &Ad[(w * 32 + i * 8) * 64]);
#pragma unroll
            for (int i = 0; i < 2; i++)
                gll16(&Bt[(size_t)(n0 + w * 16 + i * 8 + ls) * 1024 + k0 + g],
                      &Bd[(w * 16 + i * 8) * 64]);
        }
        const unsigned short* Ac = As + ((s & 1) << 13);
        const unsigned short* Bc = Bs + ((s & 1) << 12);
#pragma unroll
        for (int ks = 0; ks < 2; ks++) {
            short8 af[2], bfr[4];
#pragma unroll
            for (int mi = 0; mi < 2; mi++) {
                const int r = w * 32 + mi * 16 + l16;
                af[mi] = *reinterpret_cast<const short8*>(
                    &Ac[r * 64 + ((ks * 4 + quad) ^ (r & 7)) * 8]);
            }
#pragma unroll
            for (int ni = 0; ni < 4; ni++) {
                const int r = ni * 16 + l16;
                bfr[ni] = *reinterpret_cast<const short8*>(
                    &Bc[r * 64 + ((ks * 4 + quad) ^ (r & 7)) * 8]);
            }
#pragma unroll
            for (int mi = 0; mi < 2; mi++)
#pragma unroll
                for (int ni = 0; ni < 4; ni++)
                    acc[mi][ni] = __builtin_amdgcn_mfma_f32_16x16x32_bf16(
                        af[mi], bfr[ni], acc[mi][ni], 0, 0, 0);
        }
    }

#pragma unroll
    for (int mi = 0; mi < 2; mi++) {
        const int rl0 = w * 32 + mi * 16 + quad * 4;
        float2 rs[4];
#pragma unroll
        for (int r = 0; r < 4; r++) rs[r] = rstat_s[rl0 + r];
#pragma unroll
        for (int ni = 0; ni < 4; ni++) {
            const int col = n0 + ni * 16 + l16;
            const float uu = u[col], ww = w0[col] + bias[col];
#pragma unroll
            for (int r = 0; r < 4; r++)
                out[(size_t)(m0 + rl0 + r) * 1024 + col] =
                    fmaf(rs[r].x, acc[mi][ni][r], ww - rs[r].y * uu);
        }
    }
}

extern "C" void kernel_launch(void* const* d_in, const int* in_sizes, int n_in,
                              void* d_out, int out_size, void* d_ws, size_t ws_size,
                              hipStream_t stream) {
    const float* x      = (const float*)d_in[0];
    const float* ln1_g  = (const float*)d_in[1];
    const float* ln1_b  = (const float*)d_in[2];
    const float* w_qk   = (const float*)d_in[3];
    const float* w_v    = (const float*)d_in[4];
    const float* ln2_g  = (const float*)d_in[5];
    const float* ln2_b  = (const float*)d_in[6];
    const float* w_proj = (const float*)d_in[7];
    const float* b_proj = (const float*)d_in[8];
    float* out = (float*)d_out;

    char* ws = (char*)d_ws;
    unsigned short* xn      = (unsigned short*)(ws + 0);         // 8MB  4096x1024 bf16
    unsigned short* wqkvT   = (unsigned short*)(ws + 8388608);   // 6MB  3072x1024 bf16
    unsigned short* wgT     = (unsigned short*)(ws + 14680064);  // 2MB  1024x1024 bf16 (g2-scaled w_proj^T)
    unsigned short* qbuf    = (unsigned short*)(ws + 16777216);  // 8MB  [32][2048][64]
    unsigned short* kbuf    = (unsigned short*)(ws + 25165824);  // 8MB  [32][2048][64]
    unsigned short* vTbuf   = (unsigned short*)(ws + 33554432);  // 8MB  [32][64][2048]
    unsigned short* attn    = (unsigned short*)(ws + 41943040);  // 8MB  4096x1024 bf16 (raw, pre-LN2)
    float2*         part    = (float2*)(ws + 50331648);          // 512KB [4096][16]
    float*          u       = (float*)(ws + 50888704);           // 4KB
    float*          w0      = (float*)(ws + 50892800);           // 4KB

    hipMemsetAsync(ws + 50888704, 0, 8192, stream);              // zero u + w0
    prep<<<8192, 256, 0, stream>>>(x, ln1_g, ln1_b, w_qk, w_v, w_proj, ln2_g, ln2_b,
                                   xn, wqkvT, wgT, u, w0);
    gemm256_qkv<<<dim3(12, 16), 512, 0, stream>>>(xn, wqkvT, qbuf, kbuf, vTbuf);
    flash_attn<<<dim3(16, 32), 256, 0, stream>>>(qbuf, kbuf, vTbuf, attn, part);
    gemm_proj<<<dim3(16, 32), 256, 0, stream>>>(attn, wgT, part, u, w0, b_proj, out);
}

// Round 10
// 193.539 us; speedup vs baseline: 1.1885x; 1.0437x over previous
//
#include <hip/hip_runtime.h>
#include <hip/hip_bf16.h>

// B=2, N=2048, C=1024, H=16, hd=64, M=4096. bf16 MFMA path (threshold 2%).

typedef __attribute__((ext_vector_type(8))) short short8;
typedef __attribute__((ext_vector_type(4))) short short4v;
typedef __attribute__((ext_vector_type(4))) float float4v;
typedef __attribute__((ext_vector_type(4))) unsigned uint4v;

__device__ __forceinline__ unsigned short f2bf(float f) {   // RTNE
    unsigned u = __builtin_bit_cast(unsigned, f);
    return (unsigned short)((u + 0x7FFFu + ((u >> 16) & 1u)) >> 16);
}
// pack two f32 -> two bf16 (round-half-up) in one dword via v_perm
__device__ __forceinline__ unsigned packbf2(float lo, float hi) {
    return __builtin_amdgcn_perm(__builtin_bit_cast(unsigned, hi) + 0x8000u,
                                 __builtin_bit_cast(unsigned, lo) + 0x8000u,
                                 0x07060302u);
}
__device__ __forceinline__ void gll16(const unsigned short* g, unsigned short* l) {
    __builtin_amdgcn_global_load_lds(
        (const __attribute__((address_space(1))) unsigned int*)g,
        (__attribute__((address_space(3))) unsigned int*)l, 16, 0, 0);
}

// ---------------- prep: ln1 (blocks 0..4095) + weight transposes.
__global__ __launch_bounds__(256) void prep(
    const float* __restrict__ x, const float* __restrict__ g1, const float* __restrict__ b1,
    const float* __restrict__ w_qk, const float* __restrict__ w_v,
    const float* __restrict__ w_proj, const float* __restrict__ g2,
    const float* __restrict__ b2,
    unsigned short* __restrict__ xn, unsigned short* __restrict__ wqkvT,
    unsigned short* __restrict__ wgT, float* __restrict__ u, float* __restrict__ w0) {
    __shared__ float sh[32 * 33];
    const int bid = blockIdx.x, tid = threadIdx.x;
    if (bid < 4096) {                       // ---- LN1 row
        const float4 v = reinterpret_cast<const float4*>(x + (size_t)bid * 1024)[tid];
        float s  = v.x + v.y + v.z + v.w;
        float sq = v.x * v.x + v.y * v.y + v.z * v.z + v.w * v.w;
#pragma unroll
        for (int off = 32; off >= 1; off >>= 1) {
            s  += __shfl_xor(s, off, 64);
            sq += __shfl_xor(sq, off, 64);
        }
        const int w = tid >> 6, lane = tid & 63;
        if (lane == 0) { sh[w] = s; sh[4 + w] = sq; }
        __syncthreads();
        s  = sh[0] + sh[1] + sh[2] + sh[3];
        sq = sh[4] + sh[5] + sh[6] + sh[7];
        const float mu = s * (1.f / 1024.f);
        const float rstd = rsqrtf(sq * (1.f / 1024.f) - mu * mu + 1e-5f);
        const float4 gv = reinterpret_cast<const float4*>(g1)[tid];
        const float4 bv = reinterpret_cast<const float4*>(b1)[tid];
        ushort4 o;
        o.x = f2bf((v.x - mu) * rstd * gv.x + bv.x);
        o.y = f2bf((v.y - mu) * rstd * gv.y + bv.y);
        o.z = f2bf((v.z - mu) * rstd * gv.z + bv.z);
        o.w = f2bf((v.w - mu) * rstd * gv.w + bv.w);
        *reinterpret_cast<ushort4*>(&xn[(size_t)bid * 1024 + tid * 4]) = o;
    } else {                                // ---- transpose f32[1024][Cc] -> bf16[Cc][1024]
        const float* in; unsigned short* out; int Cc, bx, by; bool doU = false;
        if (bid < 6144)      { int t = bid - 4096; in = w_qk;   out = wqkvT;               Cc = 2048; bx = t & 63; by = t >> 6; }
        else if (bid < 7168) { int t = bid - 6144; in = w_v;    out = wqkvT + 2048 * 1024; Cc = 1024; bx = t & 31; by = t >> 5; }
        else                 { int t = bid - 7168; in = w_proj; out = wgT; doU = true;     Cc = 1024; bx = t & 31; by = t >> 5; }
        const int c0 = bx * 32, r0 = by * 32;
        const int tx = tid & 31, ty = tid >> 5;
#pragma unroll
        for (int i = 0; i < 32; i += 8)
            sh[(ty + i) * 33 + tx] = in[(size_t)(r0 + ty + i) * Cc + c0 + tx];
        __syncthreads();
        // out col = original row index c = r0+tx
        const float scale = doU ? g2[r0 + tx] : 1.f;
        const float b2v   = doU ? b2[r0 + tx] : 0.f;
#pragma unroll
        for (int i = 0; i < 32; i += 8) {
            const float raw = sh[tx * 33 + ty + i];
            const float sc  = raw * scale;
            out[(size_t)(c0 + ty + i) * 1024 + r0 + tx] = f2bf(sc);
            if (doU) {
                float pu = sc, pw = raw * b2v;    // per-c contributions for j=c0+ty+i
#pragma unroll
                for (int off = 1; off <= 16; off <<= 1) {   // reduce over tx (32 lanes)
                    pu += __shfl_xor(pu, off, 64);
                    pw += __shfl_xor(pw, off, 64);
                }
                if (tx == 0) {
                    atomicAdd(&u[c0 + ty + i], pu);
                    atomicAdd(&w0[c0 + ty + i], pw);
                }
            }
        }
    }
}

// ---------------- GEMM1: 256(m) x 192(n) tile, 512 threads, double-buffered.
// grid 16x16 = 256 blocks = exactly 1 block/CU -> 100% CU coverage (the
// 256x256 tiling had 192 blocks = 25% of CUs idle). LDS 112 KB.
// 8 waves as 4(m) x 2(n): wave tile 64(m) x 96(n), acc 4x6.
__global__ __launch_bounds__(512) void gemm_qkv(const unsigned short* __restrict__ A,
                                                const unsigned short* __restrict__ Bt,
                                                unsigned short* __restrict__ qb,
                                                unsigned short* __restrict__ kb,
                                                unsigned short* __restrict__ vT) {
    __shared__ unsigned short As[2 * 256 * 64];   // 64 KB
    __shared__ unsigned short Bs[2 * 192 * 64];   // 48 KB
    const int tid = threadIdx.x, lane = tid & 63, w = tid >> 6;     // w 0..7
    const int wm = (w >> 1) * 64, wn = (w & 1) * 96;
    const int quad = lane >> 4, l16 = lane & 15;
    const int ls = lane >> 3, sg = lane & 7;
    const int m0 = blockIdx.y * 256, n0 = blockIdx.x * 192;

    float4v acc[4][6];
#pragma unroll
    for (int mi = 0; mi < 4; mi++)
#pragma unroll
        for (int ni = 0; ni < 6; ni++) acc[mi][ni] = float4v{0.f, 0.f, 0.f, 0.f};

    const int g = (sg ^ ls) * 8;
    // stage step 0
#pragma unroll
    for (int i = 0; i < 4; i++)
        gll16(&A[(size_t)(m0 + w * 32 + i * 8 + ls) * 1024 + g], &As[(w * 32 + i * 8) * 64]);
#pragma unroll
    for (int i = 0; i < 3; i++)
        gll16(&Bt[(size_t)(n0 + w * 24 + i * 8 + ls) * 1024 + g], &Bs[(w * 24 + i * 8) * 64]);

#pragma unroll 1
    for (int s = 0; s < 16; s++) {
        __syncthreads();
        if (s + 1 < 16) {                   // stage step s+1
            const int k0 = (s + 1) << 6;
            unsigned short* Ad = As + (((s + 1) & 1) << 14);
            unsigned short* Bd = Bs + (((s + 1) & 1) * 12288);
#pragma unroll
            for (int i = 0; i < 4; i++)
                gll16(&A[(size_t)(m0 + w * 32 + i * 8 + ls) * 1024 + k0 + g],
                      &Ad[(w * 32 + i * 8) * 64]);
#pragma unroll
            for (int i = 0; i < 3; i++)
                gll16(&Bt[(size_t)(n0 + w * 24 + i * 8 + ls) * 1024 + k0 + g],
                      &Bd[(w * 24 + i * 8) * 64]);
        }
        const unsigned short* Ac = As + ((s & 1) << 14);
        const unsigned short* Bc = Bs + ((s & 1) * 12288);
#pragma unroll
        for (int ks = 0; ks < 2; ks++) {
            short8 af[4], bfr[6];
#pragma unroll
            for (int mi = 0; mi < 4; mi++) {
                const int r = wm + mi * 16 + l16;
                af[mi] = *reinterpret_cast<const short8*>(
                    &Ac[r * 64 + ((ks * 4 + quad) ^ (r & 7)) * 8]);
            }
#pragma unroll
            for (int ni = 0; ni < 6; ni++) {
                const int r = wn + ni * 16 + l16;
                bfr[ni] = *reinterpret_cast<const short8*>(
                    &Bc[r * 64 + ((ks * 4 + quad) ^ (r & 7)) * 8]);
            }
#pragma unroll
            for (int mi = 0; mi < 4; mi++)
#pragma unroll
                for (int ni = 0; ni < 6; ni++)
                    acc[mi][ni] = __builtin_amdgcn_mfma_f32_16x16x32_bf16(
                        af[mi], bfr[ni], acc[mi][ni], 0, 0, 0);
        }
    }

    const float QSCALE = 0.125f * 1.4426950408889634f;  // hd^-0.5 * log2(e)
#pragma unroll
    for (int mi = 0; mi < 4; mi++) {
        const int row0 = m0 + wm + mi * 16 + quad * 4;
        const int b = row0 >> 11, nq = row0 & 2047;
#pragma unroll
        for (int ni = 0; ni < 6; ni++) {
            const int col = n0 + wn + ni * 16 + l16;
            if (col < 1024) {             // q: [bh][n][d]
                const int h = col >> 6, d = col & 63;
#pragma unroll
                for (int r = 0; r < 4; r++)
                    qb[(((size_t)b * 16 + h) * 2048 + nq + r) * 64 + d] =
                        f2bf(acc[mi][ni][r] * QSCALE);
            } else if (col < 2048) {      // k: [bh][n][d]
                const int c = col - 1024, h = c >> 6, d = c & 63;
#pragma unroll
                for (int r = 0; r < 4; r++)
                    kb[(((size_t)b * 16 + h) * 2048 + nq + r) * 64 + d] = f2bf(acc[mi][ni][r]);
            } else {                      // v^T: [bh][d][n], 4 consecutive keys -> 8B store
                const int c = col - 2048, h = c >> 6, d = c & 63;
                const short4v sv = {(short)f2bf(acc[mi][ni][0]), (short)f2bf(acc[mi][ni][1]),
                                    (short)f2bf(acc[mi][ni][2]), (short)f2bf(acc[mi][ni][3])};
                *reinterpret_cast<short4v*>(
                    &vT[(((size_t)b * 16 + h) * 64 + d) * 2048 + nq]) = sv;
            }
        }
    }
}

// ---------------- flash attention v6 (R8 version — BK=64; R9's BK=128 cost
// occupancy, m132-style): full-rate reg-P PV via permuted-K S^T, K+V staged
// in LDS via global_load_lds, dbuf, 1 barrier/tile. Q-tile 128, 256 thr.
__global__ __launch_bounds__(256) void flash_attn(const unsigned short* __restrict__ qbuf,
                                                  const unsigned short* __restrict__ kb,
                                                  const unsigned short* __restrict__ vT,
                                                  unsigned short* __restrict__ attn,
                                                  float2* __restrict__ part) {
    __shared__ unsigned short Ks[2][64 * 64];   // K tile, permuted rows, XOR-swizzled
    __shared__ unsigned short Vs[2][64 * 64];   // V^T tile [d][key], XOR-swizzled
    const int tid = threadIdx.x, lane = tid & 63, w = tid >> 6;   // w 0..3
    const int quad = lane >> 4, l16 = lane & 15;
    const int ls = lane >> 3, sg = lane & 7;
    const int q0 = blockIdx.x * 128, bh = blockIdx.y;
    const size_t nbase = (size_t)bh * 2048;

    // K staging source rows: phys row pr holds actual key ka(pr)
    // ka = [bit5][quad(2b)][cb&1][reg(2b)] from pr = [bit5][cb&1][quad][reg]
    int srow[2];
#pragma unroll
    for (int i = 0; i < 2; i++) {
        const int pr = w * 16 + i * 8 + ls;
        srow[i] = (pr & 32) | ((pr & 12) << 1) | ((pr & 16) >> 2) | (pr & 3);
    }
    const int sgran = (sg ^ ls) << 3;

    short8 bq[2][2];   // Q as B-operand for two 16-q subblocks (q = w*32+q2*16+l16)
#pragma unroll
    for (int q2 = 0; q2 < 2; q2++)
#pragma unroll
        for (int ks = 0; ks < 2; ks++)
            bq[q2][ks] = *reinterpret_cast<const short8*>(
                &qbuf[(nbase + q0 + w * 32 + q2 * 16 + l16) * 64 + ks * 32 + quad * 8]);

    float l_part[2] = {0.f, 0.f};
    float4v o_acc[2][4];   // o_acc[q2][db][reg]: d = db*16+quad*4+reg, q = l16
#pragma unroll
    for (int q2 = 0; q2 < 2; q2++)
#pragma unroll
        for (int db = 0; db < 4; db++) o_acc[q2][db] = float4v{0.f, 0.f, 0.f, 0.f};

    // stage tile 0 (K permuted; V rows d = w*16+i*8+ls)
#pragma unroll
    for (int i = 0; i < 2; i++) {
        gll16(&kb[(nbase + srow[i]) * 64 + sgran], &Ks[0][(w * 16 + i * 8) * 64]);
        gll16(&vT[((size_t)bh * 64 + w * 16 + i * 8 + ls) * 2048 + sgran],
              &Vs[0][(w * 16 + i * 8) * 64]);
    }

#pragma unroll 1
    for (int s = 0; s < 32; s++) {
        __syncthreads();                    // drains tile-s DMA
        if (s + 1 < 32) {                   // stage tile s+1 (drained next barrier)
            const int ktn = (s + 1) << 6, buf = (s + 1) & 1;
#pragma unroll
            for (int i = 0; i < 2; i++) {
                gll16(&kb[(nbase + ktn + srow[i]) * 64 + sgran],
                      &Ks[buf][(w * 16 + i * 8) * 64]);
                gll16(&vT[((size_t)bh * 64 + w * 16 + i * 8 + ls) * 2048 + ktn + sgran],
                      &Vs[buf][(w * 16 + i * 8) * 64]);
            }
        }
        const unsigned short* Kc = Ks[s & 1];
        const unsigned short* Vc = Vs[s & 1];

        short8 kf[2][4];
#pragma unroll
        for (int ks = 0; ks < 2; ks++)
#pragma unroll
            for (int cb = 0; cb < 4; cb++) {
                const int r = cb * 16 + l16;
                kf[ks][cb] = *reinterpret_cast<const short8*>(
                    &Kc[r * 64 + ((ks * 4 + quad) ^ (r & 7)) * 8]);
            }
        // V^T A-fragments from LDS: A[m=d=db*16+l16][k=key=k2*32+quad*8+j]
        short8 va[2][4];
#pragma unroll
        for (int k2 = 0; k2 < 2; k2++)
#pragma unroll
            for (int db = 0; db < 4; db++) {
                const int r = db * 16 + l16;
                va[k2][db] = *reinterpret_cast<const short8*>(
                    &Vc[r * 64 + ((k2 * 4 + quad) ^ (r & 7)) * 8]);
            }

#pragma unroll
        for (int q2 = 0; q2 < 2; q2++) {
            float4v s_acc[4];
#pragma unroll
            for (int cb = 0; cb < 4; cb++) s_acc[cb] = float4v{0.f, 0.f, 0.f, 0.f};
#pragma unroll
            for (int ks = 0; ks < 2; ks++)
#pragma unroll
                for (int cb = 0; cb < 4; cb++)
                    s_acc[cb] = __builtin_amdgcn_mfma_f32_16x16x32_bf16(
                        kf[ks][cb], bq[q2][ks], s_acc[cb], 0, 0, 0);

            // fixed-max softmax: p = 2^s (s hard-bounded, O/l cancels).
            // pack P^T B-operand: k = quad*8 + (cb&1)*4 + reg
            float ls2 = 0.f;
            short8 pb[2];
#pragma unroll
            for (int k2 = 0; k2 < 2; k2++) {
                float p[8];
#pragma unroll
                for (int cc = 0; cc < 2; cc++)
#pragma unroll
                    for (int r = 0; r < 4; r++) {
                        const float pv = __builtin_amdgcn_exp2f(s_acc[k2 * 2 + cc][r]);
                        p[cc * 4 + r] = pv;
                        ls2 += pv;
                    }
                uint4v pd;
                pd.x = packbf2(p[0], p[1]); pd.y = packbf2(p[2], p[3]);
                pd.z = packbf2(p[4], p[5]); pd.w = packbf2(p[6], p[7]);
                pb[k2] = __builtin_bit_cast(short8, pd);
            }
            l_part[q2] += ls2;
#pragma unroll
            for (int k2 = 0; k2 < 2; k2++)
#pragma unroll
                for (int db = 0; db < 4; db++)
                    o_acc[q2][db] = __builtin_amdgcn_mfma_f32_16x16x32_bf16(
                        va[k2][db], pb[k2], o_acc[q2][db], 0, 0, 0);
        }
    }

    // epilogue: q = l16 for every value at this lane -> shuffle-free normalize
    const int b = bh >> 4, h = bh & 15;
#pragma unroll
    for (int q2 = 0; q2 < 2; q2++) {
        float lr = l_part[q2];
        lr += __shfl_xor(lr, 16, 64);
        lr += __shfl_xor(lr, 32, 64);
        const float inv = 1.f / lr;
        const int grow = b * 2048 + q0 + w * 32 + q2 * 16 + l16;
        float s = 0.f, s2 = 0.f;
#pragma unroll
        for (int db = 0; db < 4; db++) {
            const float o0 = o_acc[q2][db][0] * inv, o1 = o_acc[q2][db][1] * inv;
            const float o2 = o_acc[q2][db][2] * inv, o3 = o_acc[q2][db][3] * inv;
            const ushort4 st = {f2bf(o0), f2bf(o1), f2bf(o2), f2bf(o3)};
            *reinterpret_cast<ushort4*>(
                &attn[(size_t)grow * 1024 + h * 64 + db * 16 + quad * 4]) = st;
            s  += (o0 + o1) + (o2 + o3);
            s2 += (o0 * o0 + o1 * o1) + (o2 * o2 + o3 * o3);
        }
        s  += __shfl_xor(s, 16, 64);  s  += __shfl_xor(s, 32, 64);
        s2 += __shfl_xor(s2, 16, 64); s2 += __shfl_xor(s2, 32, 64);
        if (quad == 0) part[(size_t)grow * 16 + h] = float2{s, s2};
    }
}

// ---------------- GEMM2: attn(bf16,raw) @ Wg^T, LN2 + rowstats fused.
// Tile 128(m) x 64(n) -> grid 512 = 2 blocks/CU.
__global__ __launch_bounds__(256) void gemm_proj(const unsigned short* __restrict__ A,
                                                 const unsigned short* __restrict__ Bt,
                                                 const float2* __restrict__ part,
                                                 const float* __restrict__ u,
                                                 const float* __restrict__ w0,
                                                 const float* __restrict__ bias,
                                                 float* __restrict__ out) {
    __shared__ unsigned short As[2 * 128 * 64];   // 32 KB
    __shared__ unsigned short Bs[2 * 64 * 64];    // 16 KB
    __shared__ float2 rstat_s[128];
    const int tid = threadIdx.x, lane = tid & 63, w = tid >> 6;
    const int quad = lane >> 4, l16 = lane & 15;
    const int ls = lane >> 3, sg = lane & 7;
    const int m0 = blockIdx.y * 128, n0 = blockIdx.x * 64;
    {   // rowstats for this block's 128 rows: 2 threads/row, 8 heads each
        const int rloc = tid >> 1, half = tid & 1;
        const float4* p4 = reinterpret_cast<const float4*>(part);
        float s = 0.f, s2 = 0.f;
#pragma unroll
        for (int j = 0; j < 4; j++) {
            const float4 p = p4[(size_t)(m0 + rloc) * 8 + half * 4 + j];
            s += p.x + p.z; s2 += p.y + p.w;
        }
        s  += __shfl_xor(s, 1, 64);
        s2 += __shfl_xor(s2, 1, 64);
        if (!half) {
            const float mu = s * (1.f / 1024.f);
            const float rstd = rsqrtf(s2 * (1.f / 1024.f) - mu * mu + 1e-5f);
            rstat_s[rloc] = float2{rstd, mu * rstd};
        }
    }   // ordered before use by the K-loop's first __syncthreads()

    float4v acc[2][4];
#pragma unroll
    for (int mi = 0; mi < 2; mi++)
#pragma unroll
        for (int ni = 0; ni < 4; ni++) acc[mi][ni] = float4v{0.f, 0.f, 0.f, 0.f};

    const int g = (sg ^ ls) * 8;
    // stage step 0
#pragma unroll
    for (int i = 0; i < 4; i++)
        gll16(&A[(size_t)(m0 + w * 32 + i * 8 + ls) * 1024 + g], &As[(w * 32 + i * 8) * 64]);
#pragma unroll
    for (int i = 0; i < 2; i++)
        gll16(&Bt[(size_t)(n0 + w * 16 + i * 8 + ls) * 1024 + g], &Bs[(w * 16 + i * 8) * 64]);

#pragma unroll 1
    for (int s = 0; s < 16; s++) {
        __syncthreads();
        if (s + 1 < 16) {
            const int k0 = (s + 1) << 6;
            unsigned short* Ad = As + (((s + 1) & 1) << 13);
            unsigned short* Bd = Bs + (((s + 1) & 1) << 12);
#pragma unroll
            for (int i = 0; i < 4; i++)
                gll16(&A[(size_t)(m0 + w * 32 + i * 8 + ls) * 1024 + k0 + g],
                      &Ad[(w * 32 + i * 8) * 64]);
#pragma unroll
            for (int i = 0; i < 2; i++)
                gll16(&Bt[(size_t)(n0 + w * 16 + i * 8 + ls) * 1024 + k0 + g],
                      &Bd[(w * 16 + i * 8) * 64]);
        }
        const unsigned short* Ac = As + ((s & 1) << 13);
        const unsigned short* Bc = Bs + ((s & 1) << 12);
#pragma unroll
        for (int ks = 0; ks < 2; ks++) {
            short8 af[2], bfr[4];
#pragma unroll
            for (int mi = 0; mi < 2; mi++) {
                const int r = w * 32 + mi * 16 + l16;
                af[mi] = *reinterpret_cast<const short8*>(
                    &Ac[r * 64 + ((ks * 4 + quad) ^ (r & 7)) * 8]);
            }
#pragma unroll
            for (int ni = 0; ni < 4; ni++) {
                const int r = ni * 16 + l16;
                bfr[ni] = *reinterpret_cast<const short8*>(
                    &Bc[r * 64 + ((ks * 4 + quad) ^ (r & 7)) * 8]);
            }
#pragma unroll
            for (int mi = 0; mi < 2; mi++)
#pragma unroll
                for (int ni = 0; ni < 4; ni++)
                    acc[mi][ni] = __builtin_amdgcn_mfma_f32_16x16x32_bf16(
                        af[mi], bfr[ni], acc[mi][ni], 0, 0, 0);
        }
    }

#pragma unroll
    for (int mi = 0; mi < 2; mi++) {
        const int rl0 = w * 32 + mi * 16 + quad * 4;
        float2 rs[4];
#pragma unroll
        for (int r = 0; r < 4; r++) rs[r] = rstat_s[rl0 + r];
#pragma unroll
        for (int ni = 0; ni < 4; ni++) {
            const int col = n0 + ni * 16 + l16;
            const float uu = u[col], ww = w0[col] + bias[col];
#pragma unroll
            for (int r = 0; r < 4; r++)
                out[(size_t)(m0 + rl0 + r) * 1024 + col] =
                    fmaf(rs[r].x, acc[mi][ni][r], ww - rs[r].y * uu);
        }
    }
}

extern "C" void kernel_launch(void* const* d_in, const int* in_sizes, int n_in,
                              void* d_out, int out_size, void* d_ws, size_t ws_size,
                              hipStream_t stream) {
    const float* x      = (const float*)d_in[0];
    const float* ln1_g  = (const float*)d_in[1];
    const float* ln1_b  = (const float*)d_in[2];
    const float* w_qk   = (const float*)d_in[3];
    const float* w_v    = (const float*)d_in[4];
    const float* ln2_g  = (const float*)d_in[5];
    const float* ln2_b  = (const float*)d_in[6];
    const float* w_proj = (const float*)d_in[7];
    const float* b_proj = (const float*)d_in[8];
    float* out = (float*)d_out;

    char* ws = (char*)d_ws;
    unsigned short* xn      = (unsigned short*)(ws + 0);         // 8MB  4096x1024 bf16
    unsigned short* wqkvT   = (unsigned short*)(ws + 8388608);   // 6MB  3072x1024 bf16
    unsigned short* wgT     = (unsigned short*)(ws + 14680064);  // 2MB  1024x1024 bf16 (g2-scaled w_proj^T)
    unsigned short* qbuf    = (unsigned short*)(ws + 16777216);  // 8MB  [32][2048][64]
    unsigned short* kbuf    = (unsigned short*)(ws + 25165824);  // 8MB  [32][2048][64]
    unsigned short* vTbuf   = (unsigned short*)(ws + 33554432);  // 8MB  [32][64][2048]
    unsigned short* attn    = (unsigned short*)(ws + 41943040);  // 8MB  4096x1024 bf16 (raw, pre-LN2)
    float2*         part    = (float2*)(ws + 50331648);          // 512KB [4096][16]
    float*          u       = (float*)(ws + 50888704);           // 4KB
    float*          w0      = (float*)(ws + 50892800);           // 4KB

    hipMemsetAsync(ws + 50888704, 0, 8192, stream);              // zero u + w0
    prep<<<8192, 256, 0, stream>>>(x, ln1_g, ln1_b, w_qk, w_v, w_proj, ln2_g, ln2_b,
                                   xn, wqkvT, wgT, u, w0);
    gemm_qkv<<<dim3(16, 16), 512, 0, stream>>>(xn, wqkvT, qbuf, kbuf, vTbuf);
    flash_attn<<<dim3(16, 32), 256, 0, stream>>>(qbuf, kbuf, vTbuf, attn, part);
    gemm_proj<<<dim3(16, 32), 256, 0, stream>>>(attn, wgT, part, u, w0, b_proj, out);
}